// Round 9
// baseline (294.350 us; speedup 1.0000x reference)
//
#include <hip/hip_runtime.h>
#include <hip/hip_bf16.h>
#include <math.h>

// Problem: B=1, N=1024, D=1024, H=16, C=64, TOPK=2, HD=64, G=16
// Inputs (float32): x, Wq, Wk, Wv [1024x1024], Wg[32,1024], Wo[1024,1024]
// Output (float32): [1024,1024]
//
// GEMMs: bf16x2 split (Ah*Bh + Ah*Bl + Al*Bh), pre-split operands, 128x128
// tile (m97 shape): global_load_lds 16B staging, 48 MFMA/iter/wave.
// Attention: selection exact f32; softmax/PV use bf16 K/V (L2-BW halved).

typedef __attribute__((ext_vector_type(8))) short short8;   // 8 bf16 = 4 VGPRs
typedef __attribute__((ext_vector_type(4))) float f32x4;

#define NTOK 1024
#define DMODEL 1024
#define NHEAD 16
#define HDIM 64
#define CHUNK 64
#define NBLK 16

// async global->LDS, 16 bytes/lane; LDS dest = wave-uniform base + lane*16
__device__ __forceinline__ void load_lds16(const void* gptr, void* lptr)
{
    __builtin_amdgcn_global_load_lds(
        (const __attribute__((address_space(1))) unsigned int*)gptr,
        (__attribute__((address_space(3))) unsigned int*)lptr, 16, 0, 0);
}

// ---------------------------------------------------------------------------
// split cast: hi = bf16(v), lo = bf16(v - hi);  4 elems/thread
// ---------------------------------------------------------------------------
__global__ __launch_bounds__(256) void cast_split_f32_bf16(
    const float* __restrict__ in, __hip_bfloat16* __restrict__ hi,
    __hip_bfloat16* __restrict__ lo, int n)
{
    int i = (blockIdx.x * 256 + threadIdx.x) * 4;
    if (i < n) {
        float4 v = *(const float4*)(in + i);
        float vv[4] = {v.x, v.y, v.z, v.w};
        __hip_bfloat16 h[4], l[4];
        #pragma unroll
        for (int j = 0; j < 4; j++) {
            h[j] = __float2bfloat16(vv[j]);
            l[j] = __float2bfloat16(vv[j] - __bfloat162float(h[j]));
        }
        *(uint2*)(hi + i) = *(uint2*)h;
        *(uint2*)(lo + i) = *(uint2*)l;
    }
}

// simple cast f32 -> bf16, 4 elems/thread
__global__ __launch_bounds__(256) void cast_f32_bf16(
    const float* __restrict__ in, __hip_bfloat16* __restrict__ out, int n)
{
    int i = (blockIdx.x * 256 + threadIdx.x) * 4;
    if (i < n) {
        float4 v = *(const float4*)(in + i);
        __hip_bfloat16 t[4];
        t[0] = __float2bfloat16(v.x);
        t[1] = __float2bfloat16(v.y);
        t[2] = __float2bfloat16(v.z);
        t[3] = __float2bfloat16(v.w);
        *(uint2*)(out + i) = *(uint2*)t;
    }
}

// ---------------------------------------------------------------------------
// 128x128-tile split-GEMM body (shared by QKV and Wo kernels).
// LDS: 4 tiles [128][32] bf16 (8 KB each). Wave w: 64x64 subtile.
// Per K-iter: 8x load_lds16, 16x ds_read_b128, 48 MFMA.
// ---------------------------------------------------------------------------
#define GEMM128_BODY(Ahp, Alp, Bhp, Blp, KBEG, KEND, EPILOG)                   \
    __shared__ alignas(16) __hip_bfloat16 Ash[128*32];                          \
    __shared__ alignas(16) __hip_bfloat16 Asl[128*32];                          \
    __shared__ alignas(16) __hip_bfloat16 Bsh[128*32];                          \
    __shared__ alignas(16) __hip_bfloat16 Bsl[128*32];                          \
    const int tid  = threadIdx.x;                                               \
    const int wave = tid >> 6;                                                  \
    const int lane = tid & 63;                                                  \
    const int lr = tid >> 2;              /* staging row 0..63 */               \
    const int lc = (tid & 3) * 8;         /* staging col */                     \
    const int wm = (wave >> 1) * 64;                                            \
    const int wn = (wave & 1) * 64;                                             \
    const int fr = lane & 15;                                                   \
    const int quad = lane >> 4;                                                 \
    __hip_bfloat16* ldsAh = Ash + tid * 8;                                      \
    __hip_bfloat16* ldsAl = Asl + tid * 8;                                      \
    __hip_bfloat16* ldsBh = Bsh + tid * 8;                                      \
    __hip_bfloat16* ldsBl = Bsl + tid * 8;                                      \
    f32x4 acc[4][4] = {};                                                       \
    for (int k0 = (KBEG); k0 < (KEND); k0 += 32) {                              \
        const size_t a0 = (size_t)(m0 + lr) * DMODEL + k0 + lc;                 \
        const size_t a1 = (size_t)(m0 + 64 + lr) * DMODEL + k0 + lc;            \
        const size_t b0 = (size_t)(n0 + lr) * DMODEL + k0 + lc;                 \
        const size_t b1 = (size_t)(n0 + 64 + lr) * DMODEL + k0 + lc;            \
        load_lds16(Ahp + a0, ldsAh);                                            \
        load_lds16(Ahp + a1, ldsAh + 64 * 32);                                  \
        load_lds16(Alp + a0, ldsAl);                                            \
        load_lds16(Alp + a1, ldsAl + 64 * 32);                                  \
        load_lds16(Bhp + b0, ldsBh);                                            \
        load_lds16(Bhp + b1, ldsBh + 64 * 32);                                  \
        load_lds16(Blp + b0, ldsBl);                                            \
        load_lds16(Blp + b1, ldsBl + 64 * 32);                                  \
        __syncthreads();                                                        \
        short8 ah[4], al[4];                                                    \
        _Pragma("unroll")                                                       \
        for (int i = 0; i < 4; i++) {                                           \
            ah[i] = *(const short8*)(Ash + (wm + i * 16 + fr) * 32 + quad * 8); \
            al[i] = *(const short8*)(Asl + (wm + i * 16 + fr) * 32 + quad * 8); \
        }                                                                       \
        _Pragma("unroll")                                                       \
        for (int j = 0; j < 4; j++) {                                           \
            short8 bh = *(const short8*)(Bsh + (wn + j * 16 + fr) * 32 + quad * 8); \
            short8 bl = *(const short8*)(Bsl + (wn + j * 16 + fr) * 32 + quad * 8); \
            _Pragma("unroll")                                                   \
            for (int i = 0; i < 4; i++) {                                       \
                acc[i][j] = __builtin_amdgcn_mfma_f32_16x16x32_bf16(al[i], bh, acc[i][j], 0, 0, 0); \
                acc[i][j] = __builtin_amdgcn_mfma_f32_16x16x32_bf16(ah[i], bl, acc[i][j], 0, 0, 0); \
                acc[i][j] = __builtin_amdgcn_mfma_f32_16x16x32_bf16(ah[i], bh, acc[i][j], 0, 0, 0); \
            }                                                                   \
        }                                                                       \
        __syncthreads();                                                        \
    }                                                                           \
    _Pragma("unroll")                                                           \
    for (int i = 0; i < 4; i++)                                                 \
    _Pragma("unroll")                                                           \
    for (int j = 0; j < 4; j++)                                                 \
    _Pragma("unroll")                                                           \
    for (int r = 0; r < 4; r++) {                                               \
        int row = m0 + wm + i * 16 + quad * 4 + r;                              \
        int col = n0 + wn + j * 16 + fr;                                        \
        EPILOG;                                                                 \
    }

// QKV: blockIdx.x in [0,24): widx = x>>3 selects W/output; n0=(x&7)*128.
__global__ __launch_bounds__(256) void gemm_qkv_ps(
    const __hip_bfloat16* __restrict__ xh, const __hip_bfloat16* __restrict__ xl,
    const __hip_bfloat16* __restrict__ W3h, const __hip_bfloat16* __restrict__ W3l,
    float* __restrict__ Q, float* __restrict__ K, float* __restrict__ V)
{
    const int widx = blockIdx.x >> 3;
    const __hip_bfloat16* __restrict__ Bh = W3h + (size_t)widx * NTOK * DMODEL;
    const __hip_bfloat16* __restrict__ Bl = W3l + (size_t)widx * NTOK * DMODEL;
    float* __restrict__ C = (widx == 0) ? Q : (widx == 1) ? K : V;
    const int n0 = (blockIdx.x & 7) * 128;
    const int m0 = blockIdx.y * 128;
    GEMM128_BODY(xh, xl, Bh, Bl, 0, DMODEL,
                 C[(size_t)row * DMODEL + col] = acc[i][j][r])
}

// Wo: split-K=4, atomicAdd into zeroed C.
__global__ __launch_bounds__(256) void gemm_wo_ps(
    const __hip_bfloat16* __restrict__ Ah, const __hip_bfloat16* __restrict__ Al,
    const __hip_bfloat16* __restrict__ Bh, const __hip_bfloat16* __restrict__ Bl,
    float* __restrict__ C)
{
    const int n0 = blockIdx.x * 128;
    const int m0 = blockIdx.y * 128;
    const int kbeg = blockIdx.z * (DMODEL / 4);
    const int kend = kbeg + (DMODEL / 4);
    GEMM128_BODY(Ah, Al, Bh, Bl, kbeg, kend,
                 atomicAdd(&C[(size_t)row * DMODEL + col], acc[i][j][r]))
}

// ---------------------------------------------------------------------------
// Gate: softmax((x @ Wg^T).reshape(n, 16, 2), axis=-1) -> float2 per (n,h)
// ---------------------------------------------------------------------------
__global__ __launch_bounds__(256) void gate_kernel(
    const float* __restrict__ x,
    const float* __restrict__ Wg,
    float2* __restrict__ gate)
{
    __shared__ float gs[32];
    const int n = blockIdx.x;
    const int wave = threadIdx.x >> 6, lane = threadIdx.x & 63;
    #pragma unroll
    for (int jj = 0; jj < 8; jj++) {
        int j = wave * 8 + jj;
        float s = 0.f;
        #pragma unroll
        for (int t = 0; t < 16; t++) {
            int d = lane + (t << 6);
            s += x[n * DMODEL + d] * Wg[j * DMODEL + d];
        }
        #pragma unroll
        for (int off = 32; off; off >>= 1) s += __shfl_xor(s, off);
        if (lane == 0) gs[j] = s;
    }
    __syncthreads();
    if (threadIdx.x < NHEAD) {
        int h = threadIdx.x;
        float a = gs[2 * h], b = gs[2 * h + 1];
        float m = fmaxf(a, b);
        float ea = expf(a - m), eb = expf(b - m);
        float inv = 1.f / (ea + eb);
        gate[n * NHEAD + h] = make_float2(ea * inv, eb * inv);
    }
}

// ---------------------------------------------------------------------------
// k_compress[g][f] = mean over c of K[g*64+c][f]
// ---------------------------------------------------------------------------
__global__ __launch_bounds__(256) void kcompress_kernel(
    const float* __restrict__ K, float* __restrict__ kc)
{
    const int g = blockIdx.x;
    for (int f = threadIdx.x; f < DMODEL; f += 256) {
        float s = 0.f;
        #pragma unroll 8
        for (int c = 0; c < CHUNK; c++) s += K[(size_t)(g * CHUNK + c) * DMODEL + f];
        kc[g * DMODEL + f] = s * (1.0f / CHUNK);
    }
}

// ---------------------------------------------------------------------------
// Per-head transpose -> bf16: Ktb[(h*64+d)*1024 + n] = bf16(K[n][h*64+d])
// ---------------------------------------------------------------------------
__global__ __launch_bounds__(256) void transpose_k_kernel(
    const float* __restrict__ K, __hip_bfloat16* __restrict__ Ktb)
{
    __shared__ float T[64][65];
    const int h = blockIdx.x & 15;
    const int n0 = (blockIdx.x >> 4) * 64;
    for (int i = threadIdx.x; i < 64 * 64; i += 256) {
        int r = i >> 6, d = i & 63;
        T[r][d] = K[(size_t)(n0 + r) * DMODEL + h * HDIM + d];
    }
    __syncthreads();
    for (int i = threadIdx.x; i < 64 * 64; i += 256) {
        int d = i >> 6, nn = i & 63;
        Ktb[(size_t)(h * HDIM + d) * NTOK + n0 + nn] = __float2bfloat16(T[nn][d]);
    }
}

// ---------------------------------------------------------------------------
// score + top-2 per (n,h), transposed store idx_t[h*1024+n]. EXACT f32.
// g masked if n >= 64*g; ties -> lowest index; all-masked -> (0,1).
// ---------------------------------------------------------------------------
__global__ __launch_bounds__(256) void score_top2_kernel(
    const float* __restrict__ Q, const float* __restrict__ kc,
    int2* __restrict__ idx_t)
{
    const int t = blockIdx.x * 256 + threadIdx.x;   // t = n*16 + h
    const int n = t >> 4, h = t & 15;
    float q[HDIM];
    #pragma unroll
    for (int d = 0; d < HDIM; d++) q[d] = Q[(size_t)n * DMODEL + h * HDIM + d];
    float sc[NBLK];
    #pragma unroll
    for (int g = 0; g < NBLK; g++) {
        float s = 0.f;
        #pragma unroll
        for (int d = 0; d < HDIM; d++) s += q[d] * kc[g * DMODEL + h * HDIM + d];
        sc[g] = (n >= (g << 6)) ? -INFINITY : s;
    }
    int i1 = -1; float b1 = -INFINITY;
    #pragma unroll
    for (int g = 0; g < NBLK; g++) if (i1 < 0 || sc[g] > b1) { b1 = sc[g]; i1 = g; }
    int i2 = -1; float b2 = -INFINITY;
    #pragma unroll
    for (int g = 0; g < NBLK; g++) { if (g == i1) continue; if (i2 < 0 || sc[g] > b2) { b2 = sc[g]; i2 = g; } }
    idx_t[(h << 10) | n] = make_int2(i1, i2);
}

// ---------------------------------------------------------------------------
// FUSED attention: one wave per (n,h). inter (2 blocks) + causal intra +
// gated blend, in-place over Q. K/V read as bf16 (Ktb coalesced, Vb coalesced).
// ---------------------------------------------------------------------------
__global__ __launch_bounds__(256) void attn_fused_kernel(
    float* __restrict__ Q, const __hip_bfloat16* __restrict__ Ktb,
    const __hip_bfloat16* __restrict__ Vb, const int2* __restrict__ idx_t,
    const float2* __restrict__ gate)
{
    const int wave = threadIdx.x >> 6, lane = threadIdx.x & 63;
    const int gw = blockIdx.x * 4 + wave;   // = n*16 + h
    const int n = gw >> 4, h = gw & 15;
    const int qi = n & 63;
    const int rown = (n >> 6) * CHUNK;
    const int2 sel = idx_t[(h << 10) | n];
    const int r1 = sel.x * CHUNK, r2 = sel.y * CHUNK;

    const float qreg = Q[(size_t)n * DMODEL + h * HDIM + lane];
    const __hip_bfloat16* Kth = Ktb + (size_t)h * HDIM * NTOK;

    float s0a = 0.f, s0b = 0.f, s1a = 0.f, s1b = 0.f, sia = 0.f, sib = 0.f;
    #pragma unroll 8
    for (int d = 0; d < HDIM; d += 2) {
        float qd0 = __shfl(qreg, d);
        float qd1 = __shfl(qreg, d + 1);
        const __hip_bfloat16* row0 = Kth + (size_t)d * NTOK;
        const __hip_bfloat16* row1 = row0 + NTOK;
        s0a += qd0 * __bfloat162float(row0[r1 + lane]);
        s1a += qd0 * __bfloat162float(row0[r2 + lane]);
        sia += qd0 * __bfloat162float(row0[rown + lane]);
        s0b += qd1 * __bfloat162float(row1[r1 + lane]);
        s1b += qd1 * __bfloat162float(row1[r2 + lane]);
        sib += qd1 * __bfloat162float(row1[rown + lane]);
    }
    const float s0 = (s0a + s0b) * 0.125f;
    const float s1 = (s1a + s1b) * 0.125f;
    const float si = (sia + sib) * 0.125f;

    float m = fmaxf(s0, s1);
    #pragma unroll
    for (int off = 32; off; off >>= 1) m = fmaxf(m, __shfl_xor(m, off));
    const float e0 = expf(s0 - m), e1 = expf(s1 - m);
    float sum = e0 + e1;
    #pragma unroll
    for (int off = 32; off; off >>= 1) sum += __shfl_xor(sum, off);

    float sim = (lane > qi) ? -INFINITY : si;
    float mi = sim;
    #pragma unroll
    for (int off = 32; off; off >>= 1) mi = fmaxf(mi, __shfl_xor(mi, off));
    const float ei = (lane > qi) ? 0.f : expf(si - mi);
    float sumi = ei;
    #pragma unroll
    for (int off = 32; off; off >>= 1) sumi += __shfl_xor(sumi, off);

    const __hip_bfloat16* Vh = Vb + h * HDIM + lane;
    float oa = 0.f, ob = 0.f, oi = 0.f;
    #pragma unroll 4
    for (int k = 0; k < CHUNK; k++) {
        oa += __shfl(e0, k) * __bfloat162float(Vh[(size_t)(r1 + k) * DMODEL]);
        ob += __shfl(e1, k) * __bfloat162float(Vh[(size_t)(r2 + k) * DMODEL]);
    }
    #pragma unroll 4
    for (int k = 0; k <= qi; k++) {
        oi += __shfl(ei, k) * __bfloat162float(Vh[(size_t)(rown + k) * DMODEL]);
    }

    const float2 gt = gate[gw];
    const float val = gt.x * ((oa + ob) / sum) + gt.y * (oi / sumi);
    Q[(size_t)n * DMODEL + h * HDIM + lane] = val;
}

// ---------------------------------------------------------------------------
extern "C" void kernel_launch(void* const* d_in, const int* in_sizes, int n_in,
                              void* d_out, int out_size, void* d_ws, size_t ws_size,
                              hipStream_t stream)
{
    const float* x  = (const float*)d_in[0];
    const float* Wq = (const float*)d_in[1];
    const float* Wk = (const float*)d_in[2];
    const float* Wv = (const float*)d_in[3];
    const float* Wg = (const float*)d_in[4];
    const float* Wo = (const float*)d_in[5];

    const size_t M1 = (size_t)NTOK * DMODEL;   // 1M elems

    // workspace layout (~32.3 MB)
    float* Q       = (float*)d_ws;                    // 4 MB
    float* K       = Q + M1;                          // 4 MB
    float* V       = K + M1;                          // 4 MB
    __hip_bfloat16* Ktb = (__hip_bfloat16*)(V + M1);  // 2 MB
    __hip_bfloat16* Vb  = Ktb + M1;                   // 2 MB
    float* kc      = (float*)(Vb + M1);               // 64 KB
    float2* gate   = (float2*)(kc + NBLK * DMODEL);   // 128 KB
    int2* idx_t    = (int2*)(gate + NTOK * NHEAD);    // 128 KB
    __hip_bfloat16* xh  = (__hip_bfloat16*)(idx_t + NTOK * NHEAD);  // 2 MB (later: o hi)
    __hip_bfloat16* xl  = xh + M1;                                   // 2 MB (later: o lo)
    __hip_bfloat16* W3h = xl + M1;                                   // 6 MB (later: Wo hi)
    __hip_bfloat16* W3l = W3h + 3 * M1;                              // 6 MB (later: Wo lo)

    const int CAST_BLOCKS = (int)(M1 / (256 * 4));

    cast_split_f32_bf16<<<CAST_BLOCKS, 256, 0, stream>>>(x,  xh,         xl,         (int)M1);
    cast_split_f32_bf16<<<CAST_BLOCKS, 256, 0, stream>>>(Wq, W3h,        W3l,        (int)M1);
    cast_split_f32_bf16<<<CAST_BLOCKS, 256, 0, stream>>>(Wk, W3h + M1,   W3l + M1,   (int)M1);
    cast_split_f32_bf16<<<CAST_BLOCKS, 256, 0, stream>>>(Wv, W3h + 2*M1, W3l + 2*M1, (int)M1);

    dim3 gqkv(24, 8);
    gemm_qkv_ps<<<gqkv, 256, 0, stream>>>(xh, xl, W3h, W3l, Q, K, V);

    gate_kernel<<<NTOK, 256, 0, stream>>>(x, Wg, gate);
    kcompress_kernel<<<NBLK, 256, 0, stream>>>(K, kc);
    transpose_k_kernel<<<256, 256, 0, stream>>>(K, Ktb);
    cast_f32_bf16<<<CAST_BLOCKS, 256, 0, stream>>>(V, Vb, (int)M1);
    score_top2_kernel<<<NTOK * NHEAD / 256, 256, 0, stream>>>(Q, kc, idx_t);
    attn_fused_kernel<<<NTOK * NHEAD / 4, 256, 0, stream>>>(Q, Ktb, Vb, idx_t, gate);

    // split blended o (in Q) and Wo; reuse xh/xl and front of W3h/W3l
    cast_split_f32_bf16<<<CAST_BLOCKS, 256, 0, stream>>>(Q,  xh,  xl,  (int)M1);
    cast_split_f32_bf16<<<CAST_BLOCKS, 256, 0, stream>>>(Wo, W3h, W3l, (int)M1);

    hipMemsetAsync(d_out, 0, M1 * sizeof(float), stream);
    dim3 gwo(8, 8, 4);
    gemm_wo_ps<<<gwo, 256, 0, stream>>>(xh, xl, W3h, W3l, (float*)d_out);
}

// Round 10
// 281.494 us; speedup vs baseline: 1.0457x; 1.0457x over previous
//
#include <hip/hip_runtime.h>
#include <hip/hip_bf16.h>
#include <math.h>

// Problem: B=1, N=1024, D=1024, H=16, C=64, TOPK=2, HD=64, G=16
// Inputs (float32): x, Wq, Wk, Wv [1024x1024], Wg[32,1024], Wo[1024,1024]
// Output (float32): [1024,1024]
//
// GEMMs: bf16x2 split (hi/lo) for Q,K,o,Wo paths (selection + output accuracy);
// V projection plain bf16 (V gets truncated to bf16 for attention anyway).
// Pre-split operands; 64x64 tiles, split-K=2, padded LDS (stride 40, no bank
// conflicts). Attention: one wave per (n,h); wave-uniform broadcasts via
// v_readlane (SGPR) instead of ds_bpermute to unload the LDS pipe.

typedef __attribute__((ext_vector_type(8))) short short8;   // 8 bf16 = 4 VGPRs
typedef __attribute__((ext_vector_type(4))) float f32x4;

#define NTOK 1024
#define DMODEL 1024
#define NHEAD 16
#define HDIM 64
#define CHUNK 64
#define NBLK 16

// wave-uniform lane broadcast via v_readlane (no LDS pipe)
__device__ __forceinline__ float rl(float v, int l)
{
    return __int_as_float(__builtin_amdgcn_readlane(__float_as_int(v), l));
}

// ---------------------------------------------------------------------------
// split cast: hi = bf16(v), lo = bf16(v - hi);  4 elems/thread
// ---------------------------------------------------------------------------
__global__ __launch_bounds__(256) void cast_split_f32_bf16(
    const float* __restrict__ in, __hip_bfloat16* __restrict__ hi,
    __hip_bfloat16* __restrict__ lo, int n)
{
    int i = (blockIdx.x * 256 + threadIdx.x) * 4;
    if (i < n) {
        float4 v = *(const float4*)(in + i);
        float vv[4] = {v.x, v.y, v.z, v.w};
        __hip_bfloat16 h[4], l[4];
        #pragma unroll
        for (int j = 0; j < 4; j++) {
            h[j] = __float2bfloat16(vv[j]);
            l[j] = __float2bfloat16(vv[j] - __bfloat162float(h[j]));
        }
        *(uint2*)(hi + i) = *(uint2*)h;
        *(uint2*)(lo + i) = *(uint2*)l;
    }
}

// simple cast f32 -> bf16, 4 elems/thread
__global__ __launch_bounds__(256) void cast_f32_bf16(
    const float* __restrict__ in, __hip_bfloat16* __restrict__ out, int n)
{
    int i = (blockIdx.x * 256 + threadIdx.x) * 4;
    if (i < n) {
        float4 v = *(const float4*)(in + i);
        __hip_bfloat16 t[4];
        t[0] = __float2bfloat16(v.x);
        t[1] = __float2bfloat16(v.y);
        t[2] = __float2bfloat16(v.z);
        t[3] = __float2bfloat16(v.w);
        *(uint2*)(out + i) = *(uint2*)t;
    }
}

// ---------------------------------------------------------------------------
// QKV GEMM, 64x64 tile, split-K=2, atomicAdd epilogue (exactly 2 addends ->
// deterministic). widx = blockIdx.x>>4: 0=Q (split), 1=K (split), 2=V (hh only)
// ---------------------------------------------------------------------------
__global__ __launch_bounds__(256) void gemm_qkv_ps(
    const __hip_bfloat16* __restrict__ xh, const __hip_bfloat16* __restrict__ xl,
    const __hip_bfloat16* __restrict__ W3h, const __hip_bfloat16* __restrict__ W3l,
    float* __restrict__ Q, float* __restrict__ K, float* __restrict__ V)
{
    __shared__ alignas(16) __hip_bfloat16 Ash[64][40];
    __shared__ alignas(16) __hip_bfloat16 Asl[64][40];
    __shared__ alignas(16) __hip_bfloat16 Bsh[64][40];
    __shared__ alignas(16) __hip_bfloat16 Bsl[64][40];

    const int widx = blockIdx.x >> 4;
    const __hip_bfloat16* __restrict__ Bh = W3h + (size_t)widx * NTOK * DMODEL;
    const __hip_bfloat16* __restrict__ Bl = W3l + (size_t)widx * NTOK * DMODEL;
    float* __restrict__ C = (widx == 0) ? Q : (widx == 1) ? K : V;
    const int n0 = (blockIdx.x & 15) * 64;
    const int m0 = blockIdx.y * 64;
    const int kbeg = blockIdx.z * (DMODEL / 2);
    const int kend = kbeg + (DMODEL / 2);

    const int tid  = threadIdx.x;
    const int wave = tid >> 6;
    const int lane = tid & 63;
    const int lr = tid >> 2;
    const int lc = (tid & 3) * 8;
    const int wm = (wave >> 1) * 32;
    const int wn = (wave & 1) * 32;
    const int fr = lane & 15;
    const int quad = lane >> 4;

    f32x4 acc[2][2] = {};

    if (widx < 2) {
        for (int k0 = kbeg; k0 < kend; k0 += 32) {
            const size_t aoff = (size_t)(m0 + lr) * DMODEL + k0 + lc;
            const size_t boff = (size_t)(n0 + lr) * DMODEL + k0 + lc;
            *(uint4*)(&Ash[lr][lc]) = *(const uint4*)(xh + aoff);
            *(uint4*)(&Asl[lr][lc]) = *(const uint4*)(xl + aoff);
            *(uint4*)(&Bsh[lr][lc]) = *(const uint4*)(Bh + boff);
            *(uint4*)(&Bsl[lr][lc]) = *(const uint4*)(Bl + boff);
            __syncthreads();

            short8 a0h = *(const short8*)(&Ash[wm + fr][quad * 8]);
            short8 a1h = *(const short8*)(&Ash[wm + 16 + fr][quad * 8]);
            short8 a0l = *(const short8*)(&Asl[wm + fr][quad * 8]);
            short8 a1l = *(const short8*)(&Asl[wm + 16 + fr][quad * 8]);
            short8 b0h = *(const short8*)(&Bsh[wn + fr][quad * 8]);
            short8 b1h = *(const short8*)(&Bsh[wn + 16 + fr][quad * 8]);
            short8 b0l = *(const short8*)(&Bsl[wn + fr][quad * 8]);
            short8 b1l = *(const short8*)(&Bsl[wn + 16 + fr][quad * 8]);

            acc[0][0] = __builtin_amdgcn_mfma_f32_16x16x32_bf16(a0l, b0h, acc[0][0], 0, 0, 0);
            acc[0][1] = __builtin_amdgcn_mfma_f32_16x16x32_bf16(a0l, b1h, acc[0][1], 0, 0, 0);
            acc[1][0] = __builtin_amdgcn_mfma_f32_16x16x32_bf16(a1l, b0h, acc[1][0], 0, 0, 0);
            acc[1][1] = __builtin_amdgcn_mfma_f32_16x16x32_bf16(a1l, b1h, acc[1][1], 0, 0, 0);
            acc[0][0] = __builtin_amdgcn_mfma_f32_16x16x32_bf16(a0h, b0l, acc[0][0], 0, 0, 0);
            acc[0][1] = __builtin_amdgcn_mfma_f32_16x16x32_bf16(a0h, b1l, acc[0][1], 0, 0, 0);
            acc[1][0] = __builtin_amdgcn_mfma_f32_16x16x32_bf16(a1h, b0l, acc[1][0], 0, 0, 0);
            acc[1][1] = __builtin_amdgcn_mfma_f32_16x16x32_bf16(a1h, b1l, acc[1][1], 0, 0, 0);
            acc[0][0] = __builtin_amdgcn_mfma_f32_16x16x32_bf16(a0h, b0h, acc[0][0], 0, 0, 0);
            acc[0][1] = __builtin_amdgcn_mfma_f32_16x16x32_bf16(a0h, b1h, acc[0][1], 0, 0, 0);
            acc[1][0] = __builtin_amdgcn_mfma_f32_16x16x32_bf16(a1h, b0h, acc[1][0], 0, 0, 0);
            acc[1][1] = __builtin_amdgcn_mfma_f32_16x16x32_bf16(a1h, b1h, acc[1][1], 0, 0, 0);
            __syncthreads();
        }
    } else {
        for (int k0 = kbeg; k0 < kend; k0 += 32) {
            const size_t aoff = (size_t)(m0 + lr) * DMODEL + k0 + lc;
            const size_t boff = (size_t)(n0 + lr) * DMODEL + k0 + lc;
            *(uint4*)(&Ash[lr][lc]) = *(const uint4*)(xh + aoff);
            *(uint4*)(&Bsh[lr][lc]) = *(const uint4*)(Bh + boff);
            __syncthreads();

            short8 a0h = *(const short8*)(&Ash[wm + fr][quad * 8]);
            short8 a1h = *(const short8*)(&Ash[wm + 16 + fr][quad * 8]);
            short8 b0h = *(const short8*)(&Bsh[wn + fr][quad * 8]);
            short8 b1h = *(const short8*)(&Bsh[wn + 16 + fr][quad * 8]);

            acc[0][0] = __builtin_amdgcn_mfma_f32_16x16x32_bf16(a0h, b0h, acc[0][0], 0, 0, 0);
            acc[0][1] = __builtin_amdgcn_mfma_f32_16x16x32_bf16(a0h, b1h, acc[0][1], 0, 0, 0);
            acc[1][0] = __builtin_amdgcn_mfma_f32_16x16x32_bf16(a1h, b0h, acc[1][0], 0, 0, 0);
            acc[1][1] = __builtin_amdgcn_mfma_f32_16x16x32_bf16(a1h, b1h, acc[1][1], 0, 0, 0);
            __syncthreads();
        }
    }

    #pragma unroll
    for (int tm = 0; tm < 2; tm++)
    #pragma unroll
    for (int tn = 0; tn < 2; tn++)
    #pragma unroll
    for (int r = 0; r < 4; r++) {
        int row = m0 + wm + tm * 16 + quad * 4 + r;
        int col = n0 + wn + tn * 16 + fr;
        atomicAdd(&C[(size_t)row * DMODEL + col], acc[tm][tn][r]);
    }
}

// ---------------------------------------------------------------------------
// Wo GEMM (split operands), 64x64 tile, split-K=2, atomicAdd into zeroed C.
// ---------------------------------------------------------------------------
__global__ __launch_bounds__(256) void gemm_wo_ps(
    const __hip_bfloat16* __restrict__ Ah, const __hip_bfloat16* __restrict__ Al,
    const __hip_bfloat16* __restrict__ Bh, const __hip_bfloat16* __restrict__ Bl,
    float* __restrict__ C)
{
    __shared__ alignas(16) __hip_bfloat16 Ash[64][40];
    __shared__ alignas(16) __hip_bfloat16 Asl[64][40];
    __shared__ alignas(16) __hip_bfloat16 Bsh[64][40];
    __shared__ alignas(16) __hip_bfloat16 Bsl[64][40];

    const int n0 = blockIdx.x * 64;
    const int m0 = blockIdx.y * 64;
    const int kbeg = blockIdx.z * (DMODEL / 2);
    const int kend = kbeg + (DMODEL / 2);

    const int tid  = threadIdx.x;
    const int wave = tid >> 6;
    const int lane = tid & 63;
    const int lr = tid >> 2;
    const int lc = (tid & 3) * 8;
    const int wm = (wave >> 1) * 32;
    const int wn = (wave & 1) * 32;
    const int fr = lane & 15;
    const int quad = lane >> 4;

    f32x4 acc[2][2] = {};

    for (int k0 = kbeg; k0 < kend; k0 += 32) {
        const size_t aoff = (size_t)(m0 + lr) * DMODEL + k0 + lc;
        const size_t boff = (size_t)(n0 + lr) * DMODEL + k0 + lc;
        *(uint4*)(&Ash[lr][lc]) = *(const uint4*)(Ah + aoff);
        *(uint4*)(&Asl[lr][lc]) = *(const uint4*)(Al + aoff);
        *(uint4*)(&Bsh[lr][lc]) = *(const uint4*)(Bh + boff);
        *(uint4*)(&Bsl[lr][lc]) = *(const uint4*)(Bl + boff);
        __syncthreads();

        short8 a0h = *(const short8*)(&Ash[wm + fr][quad * 8]);
        short8 a1h = *(const short8*)(&Ash[wm + 16 + fr][quad * 8]);
        short8 a0l = *(const short8*)(&Asl[wm + fr][quad * 8]);
        short8 a1l = *(const short8*)(&Asl[wm + 16 + fr][quad * 8]);
        short8 b0h = *(const short8*)(&Bsh[wn + fr][quad * 8]);
        short8 b1h = *(const short8*)(&Bsh[wn + 16 + fr][quad * 8]);
        short8 b0l = *(const short8*)(&Bsl[wn + fr][quad * 8]);
        short8 b1l = *(const short8*)(&Bsl[wn + 16 + fr][quad * 8]);

        acc[0][0] = __builtin_amdgcn_mfma_f32_16x16x32_bf16(a0l, b0h, acc[0][0], 0, 0, 0);
        acc[0][1] = __builtin_amdgcn_mfma_f32_16x16x32_bf16(a0l, b1h, acc[0][1], 0, 0, 0);
        acc[1][0] = __builtin_amdgcn_mfma_f32_16x16x32_bf16(a1l, b0h, acc[1][0], 0, 0, 0);
        acc[1][1] = __builtin_amdgcn_mfma_f32_16x16x32_bf16(a1l, b1h, acc[1][1], 0, 0, 0);
        acc[0][0] = __builtin_amdgcn_mfma_f32_16x16x32_bf16(a0h, b0l, acc[0][0], 0, 0, 0);
        acc[0][1] = __builtin_amdgcn_mfma_f32_16x16x32_bf16(a0h, b1l, acc[0][1], 0, 0, 0);
        acc[1][0] = __builtin_amdgcn_mfma_f32_16x16x32_bf16(a1h, b0l, acc[1][0], 0, 0, 0);
        acc[1][1] = __builtin_amdgcn_mfma_f32_16x16x32_bf16(a1h, b1l, acc[1][1], 0, 0, 0);
        acc[0][0] = __builtin_amdgcn_mfma_f32_16x16x32_bf16(a0h, b0h, acc[0][0], 0, 0, 0);
        acc[0][1] = __builtin_amdgcn_mfma_f32_16x16x32_bf16(a0h, b1h, acc[0][1], 0, 0, 0);
        acc[1][0] = __builtin_amdgcn_mfma_f32_16x16x32_bf16(a1h, b0h, acc[1][0], 0, 0, 0);
        acc[1][1] = __builtin_amdgcn_mfma_f32_16x16x32_bf16(a1h, b1h, acc[1][1], 0, 0, 0);
        __syncthreads();
    }

    #pragma unroll
    for (int tm = 0; tm < 2; tm++)
    #pragma unroll
    for (int tn = 0; tn < 2; tn++)
    #pragma unroll
    for (int r = 0; r < 4; r++) {
        int row = m0 + wm + tm * 16 + quad * 4 + r;
        int col = n0 + wn + tn * 16 + fr;
        atomicAdd(&C[(size_t)row * DMODEL + col], acc[tm][tn][r]);
    }
}

// ---------------------------------------------------------------------------
// Gate: softmax((x @ Wg^T).reshape(n, 16, 2), axis=-1) -> float2 per (n,h)
// ---------------------------------------------------------------------------
__global__ __launch_bounds__(256) void gate_kernel(
    const float* __restrict__ x,
    const float* __restrict__ Wg,
    float2* __restrict__ gate)
{
    __shared__ float gs[32];
    const int n = blockIdx.x;
    const int wave = threadIdx.x >> 6, lane = threadIdx.x & 63;
    #pragma unroll
    for (int jj = 0; jj < 8; jj++) {
        int j = wave * 8 + jj;
        float s = 0.f;
        #pragma unroll
        for (int t = 0; t < 16; t++) {
            int d = lane + (t << 6);
            s += x[n * DMODEL + d] * Wg[j * DMODEL + d];
        }
        #pragma unroll
        for (int off = 32; off; off >>= 1) s += __shfl_xor(s, off);
        if (lane == 0) gs[j] = s;
    }
    __syncthreads();
    if (threadIdx.x < NHEAD) {
        int h = threadIdx.x;
        float a = gs[2 * h], b = gs[2 * h + 1];
        float m = fmaxf(a, b);
        float ea = expf(a - m), eb = expf(b - m);
        float inv = 1.f / (ea + eb);
        gate[n * NHEAD + h] = make_float2(ea * inv, eb * inv);
    }
}

// ---------------------------------------------------------------------------
// k_compress[g][f] = mean over c of K[g*64+c][f]
// ---------------------------------------------------------------------------
__global__ __launch_bounds__(256) void kcompress_kernel(
    const float* __restrict__ K, float* __restrict__ kc)
{
    const int g = blockIdx.x;
    for (int f = threadIdx.x; f < DMODEL; f += 256) {
        float s = 0.f;
        #pragma unroll 8
        for (int c = 0; c < CHUNK; c++) s += K[(size_t)(g * CHUNK + c) * DMODEL + f];
        kc[g * DMODEL + f] = s * (1.0f / CHUNK);
    }
}

// ---------------------------------------------------------------------------
// Per-head transpose -> bf16: Ktb[(h*64+d)*1024 + n] = bf16(K[n][h*64+d])
// ---------------------------------------------------------------------------
__global__ __launch_bounds__(256) void transpose_k_kernel(
    const float* __restrict__ K, __hip_bfloat16* __restrict__ Ktb)
{
    __shared__ float T[64][65];
    const int h = blockIdx.x & 15;
    const int n0 = (blockIdx.x >> 4) * 64;
    for (int i = threadIdx.x; i < 64 * 64; i += 256) {
        int r = i >> 6, d = i & 63;
        T[r][d] = K[(size_t)(n0 + r) * DMODEL + h * HDIM + d];
    }
    __syncthreads();
    for (int i = threadIdx.x; i < 64 * 64; i += 256) {
        int d = i >> 6, nn = i & 63;
        Ktb[(size_t)(h * HDIM + d) * NTOK + n0 + nn] = __float2bfloat16(T[nn][d]);
    }
}

// ---------------------------------------------------------------------------
// score + top-2 per (n,h), transposed store idx_t[h*1024+n]. EXACT f32.
// g masked if n >= 64*g; ties -> lowest index; all-masked -> (0,1).
// ---------------------------------------------------------------------------
__global__ __launch_bounds__(256) void score_top2_kernel(
    const float* __restrict__ Q, const float* __restrict__ kc,
    int2* __restrict__ idx_t)
{
    const int t = blockIdx.x * 256 + threadIdx.x;   // t = n*16 + h
    const int n = t >> 4, h = t & 15;
    float q[HDIM];
    #pragma unroll
    for (int d = 0; d < HDIM; d++) q[d] = Q[(size_t)n * DMODEL + h * HDIM + d];
    float sc[NBLK];
    #pragma unroll
    for (int g = 0; g < NBLK; g++) {
        float s = 0.f;
        #pragma unroll
        for (int d = 0; d < HDIM; d++) s += q[d] * kc[g * DMODEL + h * HDIM + d];
        sc[g] = (n >= (g << 6)) ? -INFINITY : s;
    }
    int i1 = -1; float b1 = -INFINITY;
    #pragma unroll
    for (int g = 0; g < NBLK; g++) if (i1 < 0 || sc[g] > b1) { b1 = sc[g]; i1 = g; }
    int i2 = -1; float b2 = -INFINITY;
    #pragma unroll
    for (int g = 0; g < NBLK; g++) { if (g == i1) continue; if (i2 < 0 || sc[g] > b2) { b2 = sc[g]; i2 = g; } }
    idx_t[(h << 10) | n] = make_int2(i1, i2);
}

// ---------------------------------------------------------------------------
// FUSED attention: one wave per (n,h). inter (2 blocks) + causal intra +
// gated blend, in-place over Q. Wave-uniform broadcasts via v_readlane.
// ---------------------------------------------------------------------------
__global__ __launch_bounds__(256) void attn_fused_kernel(
    float* __restrict__ Q, const __hip_bfloat16* __restrict__ Ktb,
    const __hip_bfloat16* __restrict__ Vb, const int2* __restrict__ idx_t,
    const float2* __restrict__ gate)
{
    const int wave = threadIdx.x >> 6, lane = threadIdx.x & 63;
    const int gw = blockIdx.x * 4 + wave;   // = n*16 + h
    const int n = gw >> 4, h = gw & 15;
    const int qi = n & 63;
    const int rown = (n >> 6) * CHUNK;
    const int2 sel = idx_t[(h << 10) | n];
    const int r1 = sel.x * CHUNK, r2 = sel.y * CHUNK;

    const float qreg = Q[(size_t)n * DMODEL + h * HDIM + lane];
    const __hip_bfloat16* Kth = Ktb + (size_t)h * HDIM * NTOK;

    float s0a = 0.f, s0b = 0.f, s1a = 0.f, s1b = 0.f, sia = 0.f, sib = 0.f;
    #pragma unroll 8
    for (int d = 0; d < HDIM; d += 2) {
        float qd0 = rl(qreg, d);
        float qd1 = rl(qreg, d + 1);
        const __hip_bfloat16* row0 = Kth + (size_t)d * NTOK;
        const __hip_bfloat16* row1 = row0 + NTOK;
        s0a += qd0 * __bfloat162float(row0[r1 + lane]);
        s1a += qd0 * __bfloat162float(row0[r2 + lane]);
        sia += qd0 * __bfloat162float(row0[rown + lane]);
        s0b += qd1 * __bfloat162float(row1[r1 + lane]);
        s1b += qd1 * __bfloat162float(row1[r2 + lane]);
        sib += qd1 * __bfloat162float(row1[rown + lane]);
    }
    const float s0 = (s0a + s0b) * 0.125f;
    const float s1 = (s1a + s1b) * 0.125f;
    const float si = (sia + sib) * 0.125f;

    float m = fmaxf(s0, s1);
    #pragma unroll
    for (int off = 32; off; off >>= 1) m = fmaxf(m, __shfl_xor(m, off));
    const float e0 = expf(s0 - m), e1 = expf(s1 - m);
    float sum = e0 + e1;
    #pragma unroll
    for (int off = 32; off; off >>= 1) sum += __shfl_xor(sum, off);

    float sim = (lane > qi) ? -INFINITY : si;
    float mi = sim;
    #pragma unroll
    for (int off = 32; off; off >>= 1) mi = fmaxf(mi, __shfl_xor(mi, off));
    const float ei = (lane > qi) ? 0.f : expf(si - mi);
    float sumi = ei;
    #pragma unroll
    for (int off = 32; off; off >>= 1) sumi += __shfl_xor(sumi, off);

    const __hip_bfloat16* Vh = Vb + h * HDIM + lane;
    float oa = 0.f, ob = 0.f, oi = 0.f;
    #pragma unroll 8
    for (int k = 0; k < CHUNK; k++) {
        oa += rl(e0, k) * __bfloat162float(Vh[(size_t)(r1 + k) * DMODEL]);
        ob += rl(e1, k) * __bfloat162float(Vh[(size_t)(r2 + k) * DMODEL]);
    }
    #pragma unroll 4
    for (int k = 0; k <= qi; k++) {        // qi wave-uniform
        oi += rl(ei, k) * __bfloat162float(Vh[(size_t)(rown + k) * DMODEL]);
    }

    const float2 gt = gate[gw];
    const float val = gt.x * ((oa + ob) / sum) + gt.y * (oi / sumi);
    Q[(size_t)n * DMODEL + h * HDIM + lane] = val;
}

// ---------------------------------------------------------------------------
extern "C" void kernel_launch(void* const* d_in, const int* in_sizes, int n_in,
                              void* d_out, int out_size, void* d_ws, size_t ws_size,
                              hipStream_t stream)
{
    const float* x  = (const float*)d_in[0];
    const float* Wq = (const float*)d_in[1];
    const float* Wk = (const float*)d_in[2];
    const float* Wv = (const float*)d_in[3];
    const float* Wg = (const float*)d_in[4];
    const float* Wo = (const float*)d_in[5];

    const size_t M1 = (size_t)NTOK * DMODEL;   // 1M elems

    // workspace layout (~32.3 MB)
    float* Q       = (float*)d_ws;                    // 4 MB
    float* K       = Q + M1;                          // 4 MB
    float* V       = K + M1;                          // 4 MB
    __hip_bfloat16* Ktb = (__hip_bfloat16*)(V + M1);  // 2 MB
    __hip_bfloat16* Vb  = Ktb + M1;                   // 2 MB
    float* kc      = (float*)(Vb + M1);               // 64 KB
    float2* gate   = (float2*)(kc + NBLK * DMODEL);   // 128 KB
    int2* idx_t    = (int2*)(gate + NTOK * NHEAD);    // 128 KB
    __hip_bfloat16* xh  = (__hip_bfloat16*)(idx_t + NTOK * NHEAD);  // 2 MB (later: o hi)
    __hip_bfloat16* xl  = xh + M1;                                   // 2 MB (later: o lo)
    __hip_bfloat16* W3h = xl + M1;                                   // 6 MB (later: Wo hi)
    __hip_bfloat16* W3l = W3h + 3 * M1;                              // 6 MB (later: Wo lo)

    const int CAST_BLOCKS = (int)(M1 / (256 * 4));

    cast_split_f32_bf16<<<CAST_BLOCKS, 256, 0, stream>>>(x,  xh,       xl,       (int)M1);
    cast_split_f32_bf16<<<CAST_BLOCKS, 256, 0, stream>>>(Wq, W3h,      W3l,      (int)M1);
    cast_split_f32_bf16<<<CAST_BLOCKS, 256, 0, stream>>>(Wk, W3h + M1, W3l + M1, (int)M1);
    cast_f32_bf16<<<CAST_BLOCKS, 256, 0, stream>>>(Wv, W3h + 2*M1, (int)M1);   // V: hh only

    hipMemsetAsync(Q, 0, 3 * M1 * sizeof(float), stream);  // Q,K,V contiguous
    dim3 gqkv(48, 16, 2);
    gemm_qkv_ps<<<gqkv, 256, 0, stream>>>(xh, xl, W3h, W3l, Q, K, V);

    gate_kernel<<<NTOK, 256, 0, stream>>>(x, Wg, gate);
    kcompress_kernel<<<NBLK, 256, 0, stream>>>(K, kc);
    transpose_k_kernel<<<256, 256, 0, stream>>>(K, Ktb);
    cast_f32_bf16<<<CAST_BLOCKS, 256, 0, stream>>>(V, Vb, (int)M1);
    score_top2_kernel<<<NTOK * NHEAD / 256, 256, 0, stream>>>(Q, kc, idx_t);
    attn_fused_kernel<<<NTOK * NHEAD / 4, 256, 0, stream>>>(Q, Ktb, Vb, idx_t, gate);

    // split blended o (in Q) and Wo; reuse xh/xl and front of W3h/W3l
    cast_split_f32_bf16<<<CAST_BLOCKS, 256, 0, stream>>>(Q,  xh,  xl,  (int)M1);
    cast_split_f32_bf16<<<CAST_BLOCKS, 256, 0, stream>>>(Wo, W3h, W3l, (int)M1);

    hipMemsetAsync(d_out, 0, M1 * sizeof(float), stream);
    dim3 gwo(16, 16, 2);
    gemm_wo_ps<<<gwo, 256, 0, stream>>>(xh, xl, W3h, W3l, (float*)d_out);
}

// Round 11
// 228.715 us; speedup vs baseline: 1.2870x; 1.2308x over previous
//
#include <hip/hip_runtime.h>
#include <hip/hip_bf16.h>
#include <math.h>

// Problem: B=1, N=1024, D=1024, H=16, C=64, TOPK=2, HD=64, G=16
// Inputs (float32): x, Wq, Wk, Wv [1024x1024], Wg[32,1024], Wo[1024,1024]
// Output (float32): [1024,1024]
//
// GEMMs: bf16x2 split (hi/lo) MFMA for Q,K,o,Wo; V plain bf16. Pre-split
// operands, 64x64 tiles, padded LDS, direct stores (no split-K/atomics).
// Attention: selection exact f32 (score_top2); fused softmax/PV kernel uses
// packed-bf16-pair K/V with v_dot2_f32_bf16 (2 MACs/inst, dword loads).

typedef __attribute__((ext_vector_type(8))) short short8;   // 8 bf16 = 4 VGPRs
typedef __attribute__((ext_vector_type(4))) float f32x4;
typedef __attribute__((ext_vector_type(2))) __bf16 bf16x2v;

#define NTOK 1024
#define DMODEL 1024
#define NHEAD 16
#define HDIM 64
#define CHUNK 64
#define NBLK 16

// wave-uniform lane broadcast via v_readlane (no LDS pipe)
__device__ __forceinline__ float rl(float v, int l)
{
    return __int_as_float(__builtin_amdgcn_readlane(__float_as_int(v), l));
}
__device__ __forceinline__ unsigned rlu(unsigned v, int l)
{
    return (unsigned)__builtin_amdgcn_readlane((int)v, l);
}

// bf16 bit pattern of float
__device__ __forceinline__ unsigned short bf16bits(float v)
{
    __hip_bfloat16 h = __float2bfloat16(v);
    return __builtin_bit_cast(unsigned short, h);
}

// acc += a.lo*b.lo + a.hi*b.hi  (bf16 pairs packed in uints)
__device__ __forceinline__ float dot2bf(unsigned a, unsigned b, float acc)
{
#if __has_builtin(__builtin_amdgcn_fdot2_f32_bf16)
    return __builtin_amdgcn_fdot2_f32_bf16(
        __builtin_bit_cast(bf16x2v, a), __builtin_bit_cast(bf16x2v, b), acc, false);
#else
    float a0 = __uint_as_float(a << 16), a1 = __uint_as_float(a & 0xffff0000u);
    float b0 = __uint_as_float(b << 16), b1 = __uint_as_float(b & 0xffff0000u);
    return acc + a0 * b0 + a1 * b1;
#endif
}

// pack (own, lane^1) bf16 bits into a uint; valid at EVEN lanes (own=low)
__device__ __forceinline__ unsigned packpair(float v)
{
    unsigned b = bf16bits(v);
    unsigned nb = (unsigned)__shfl_xor((int)b, 1) & 0xffffu;
    return b | (nb << 16);
}

// ---------------------------------------------------------------------------
// Merged pre-cast: which = blockIdx.x>>10 : 0 x(split) 1 Wq(split) 2 Wk(split)
// 3 Wv (hi only). 4 elems/thread.
// ---------------------------------------------------------------------------
__global__ __launch_bounds__(256) void cast_all_kernel(
    const float* __restrict__ x, const float* __restrict__ Wq,
    const float* __restrict__ Wk, const float* __restrict__ Wv,
    __hip_bfloat16* __restrict__ xh, __hip_bfloat16* __restrict__ xl,
    __hip_bfloat16* __restrict__ W3h, __hip_bfloat16* __restrict__ W3l)
{
    const size_t M1 = (size_t)NTOK * DMODEL;
    const int which = blockIdx.x >> 10;
    const int b = blockIdx.x & 1023;
    const int i = (b * 256 + threadIdx.x) * 4;
    const float* in; __hip_bfloat16 *hi, *lo;
    if (which == 0)      { in = x;  hi = xh;            lo = xl; }
    else if (which == 1) { in = Wq; hi = W3h;           lo = W3l; }
    else if (which == 2) { in = Wk; hi = W3h + M1;      lo = W3l + M1; }
    else                 { in = Wv; hi = W3h + 2 * M1;  lo = nullptr; }

    float4 v = *(const float4*)(in + i);
    float vv[4] = {v.x, v.y, v.z, v.w};
    __hip_bfloat16 h[4], l[4];
    #pragma unroll
    for (int j = 0; j < 4; j++) {
        h[j] = __float2bfloat16(vv[j]);
        l[j] = __float2bfloat16(vv[j] - __bfloat162float(h[j]));
    }
    *(uint2*)(hi + i) = *(uint2*)h;
    if (lo) *(uint2*)(lo + i) = *(uint2*)l;
}

// Merged post-cast: which=0: o(=Q buffer) split; which=1: Wo split.
__global__ __launch_bounds__(256) void cast_owo_kernel(
    const float* __restrict__ o, const float* __restrict__ Wo,
    __hip_bfloat16* __restrict__ oh, __hip_bfloat16* __restrict__ ol,
    __hip_bfloat16* __restrict__ Wh, __hip_bfloat16* __restrict__ Wl)
{
    const int which = blockIdx.x >> 10;
    const int b = blockIdx.x & 1023;
    const int i = (b * 256 + threadIdx.x) * 4;
    const float* in = which ? Wo : o;
    __hip_bfloat16* hi = which ? Wh : oh;
    __hip_bfloat16* lo = which ? Wl : ol;
    float4 v = *(const float4*)(in + i);
    float vv[4] = {v.x, v.y, v.z, v.w};
    __hip_bfloat16 h[4], l[4];
    #pragma unroll
    for (int j = 0; j < 4; j++) {
        h[j] = __float2bfloat16(vv[j]);
        l[j] = __float2bfloat16(vv[j] - __bfloat162float(h[j]));
    }
    *(uint2*)(hi + i) = *(uint2*)h;
    *(uint2*)(lo + i) = *(uint2*)l;
}

// ---------------------------------------------------------------------------
// QKV GEMM, 64x64 tile. widx: 0=Q (split), 1=K (split), 2=V (hi only).
// ---------------------------------------------------------------------------
__global__ __launch_bounds__(256) void gemm_qkv_ps(
    const __hip_bfloat16* __restrict__ xh, const __hip_bfloat16* __restrict__ xl,
    const __hip_bfloat16* __restrict__ W3h, const __hip_bfloat16* __restrict__ W3l,
    float* __restrict__ Q, float* __restrict__ K, float* __restrict__ V)
{
    __shared__ alignas(16) __hip_bfloat16 Ash[64][40];
    __shared__ alignas(16) __hip_bfloat16 Asl[64][40];
    __shared__ alignas(16) __hip_bfloat16 Bsh[64][40];
    __shared__ alignas(16) __hip_bfloat16 Bsl[64][40];

    const int widx = blockIdx.x >> 4;
    const __hip_bfloat16* __restrict__ Bh = W3h + (size_t)widx * NTOK * DMODEL;
    const __hip_bfloat16* __restrict__ Bl = W3l + (size_t)widx * NTOK * DMODEL;
    float* __restrict__ C = (widx == 0) ? Q : (widx == 1) ? K : V;
    const int n0 = (blockIdx.x & 15) * 64;
    const int m0 = blockIdx.y * 64;

    const int tid  = threadIdx.x;
    const int wave = tid >> 6;
    const int lane = tid & 63;
    const int lr = tid >> 2;
    const int lc = (tid & 3) * 8;
    const int wm = (wave >> 1) * 32;
    const int wn = (wave & 1) * 32;
    const int fr = lane & 15;
    const int quad = lane >> 4;

    f32x4 acc[2][2] = {};

    if (widx < 2) {
        for (int k0 = 0; k0 < DMODEL; k0 += 32) {
            const size_t aoff = (size_t)(m0 + lr) * DMODEL + k0 + lc;
            const size_t boff = (size_t)(n0 + lr) * DMODEL + k0 + lc;
            *(uint4*)(&Ash[lr][lc]) = *(const uint4*)(xh + aoff);
            *(uint4*)(&Asl[lr][lc]) = *(const uint4*)(xl + aoff);
            *(uint4*)(&Bsh[lr][lc]) = *(const uint4*)(Bh + boff);
            *(uint4*)(&Bsl[lr][lc]) = *(const uint4*)(Bl + boff);
            __syncthreads();

            short8 a0h = *(const short8*)(&Ash[wm + fr][quad * 8]);
            short8 a1h = *(const short8*)(&Ash[wm + 16 + fr][quad * 8]);
            short8 a0l = *(const short8*)(&Asl[wm + fr][quad * 8]);
            short8 a1l = *(const short8*)(&Asl[wm + 16 + fr][quad * 8]);
            short8 b0h = *(const short8*)(&Bsh[wn + fr][quad * 8]);
            short8 b1h = *(const short8*)(&Bsh[wn + 16 + fr][quad * 8]);
            short8 b0l = *(const short8*)(&Bsl[wn + fr][quad * 8]);
            short8 b1l = *(const short8*)(&Bsl[wn + 16 + fr][quad * 8]);

            acc[0][0] = __builtin_amdgcn_mfma_f32_16x16x32_bf16(a0l, b0h, acc[0][0], 0, 0, 0);
            acc[0][1] = __builtin_amdgcn_mfma_f32_16x16x32_bf16(a0l, b1h, acc[0][1], 0, 0, 0);
            acc[1][0] = __builtin_amdgcn_mfma_f32_16x16x32_bf16(a1l, b0h, acc[1][0], 0, 0, 0);
            acc[1][1] = __builtin_amdgcn_mfma_f32_16x16x32_bf16(a1l, b1h, acc[1][1], 0, 0, 0);
            acc[0][0] = __builtin_amdgcn_mfma_f32_16x16x32_bf16(a0h, b0l, acc[0][0], 0, 0, 0);
            acc[0][1] = __builtin_amdgcn_mfma_f32_16x16x32_bf16(a0h, b1l, acc[0][1], 0, 0, 0);
            acc[1][0] = __builtin_amdgcn_mfma_f32_16x16x32_bf16(a1h, b0l, acc[1][0], 0, 0, 0);
            acc[1][1] = __builtin_amdgcn_mfma_f32_16x16x32_bf16(a1h, b1l, acc[1][1], 0, 0, 0);
            acc[0][0] = __builtin_amdgcn_mfma_f32_16x16x32_bf16(a0h, b0h, acc[0][0], 0, 0, 0);
            acc[0][1] = __builtin_amdgcn_mfma_f32_16x16x32_bf16(a0h, b1h, acc[0][1], 0, 0, 0);
            acc[1][0] = __builtin_amdgcn_mfma_f32_16x16x32_bf16(a1h, b0h, acc[1][0], 0, 0, 0);
            acc[1][1] = __builtin_amdgcn_mfma_f32_16x16x32_bf16(a1h, b1h, acc[1][1], 0, 0, 0);
            __syncthreads();
        }
    } else {
        for (int k0 = 0; k0 < DMODEL; k0 += 32) {
            const size_t aoff = (size_t)(m0 + lr) * DMODEL + k0 + lc;
            const size_t boff = (size_t)(n0 + lr) * DMODEL + k0 + lc;
            *(uint4*)(&Ash[lr][lc]) = *(const uint4*)(xh + aoff);
            *(uint4*)(&Bsh[lr][lc]) = *(const uint4*)(Bh + boff);
            __syncthreads();

            short8 a0h = *(const short8*)(&Ash[wm + fr][quad * 8]);
            short8 a1h = *(const short8*)(&Ash[wm + 16 + fr][quad * 8]);
            short8 b0h = *(const short8*)(&Bsh[wn + fr][quad * 8]);
            short8 b1h = *(const short8*)(&Bsh[wn + 16 + fr][quad * 8]);

            acc[0][0] = __builtin_amdgcn_mfma_f32_16x16x32_bf16(a0h, b0h, acc[0][0], 0, 0, 0);
            acc[0][1] = __builtin_amdgcn_mfma_f32_16x16x32_bf16(a0h, b1h, acc[0][1], 0, 0, 0);
            acc[1][0] = __builtin_amdgcn_mfma_f32_16x16x32_bf16(a1h, b0h, acc[1][0], 0, 0, 0);
            acc[1][1] = __builtin_amdgcn_mfma_f32_16x16x32_bf16(a1h, b1h, acc[1][1], 0, 0, 0);
            __syncthreads();
        }
    }

    #pragma unroll
    for (int tm = 0; tm < 2; tm++)
    #pragma unroll
    for (int tn = 0; tn < 2; tn++)
    #pragma unroll
    for (int r = 0; r < 4; r++) {
        int row = m0 + wm + tm * 16 + quad * 4 + r;
        int col = n0 + wn + tn * 16 + fr;
        C[(size_t)row * DMODEL + col] = acc[tm][tn][r];
    }
}

// ---------------------------------------------------------------------------
// Wo GEMM (split operands), 64x64 tile, direct store.
// ---------------------------------------------------------------------------
__global__ __launch_bounds__(256) void gemm_wo_ps(
    const __hip_bfloat16* __restrict__ Ah, const __hip_bfloat16* __restrict__ Al,
    const __hip_bfloat16* __restrict__ Bh, const __hip_bfloat16* __restrict__ Bl,
    float* __restrict__ C)
{
    __shared__ alignas(16) __hip_bfloat16 Ash[64][40];
    __shared__ alignas(16) __hip_bfloat16 Asl[64][40];
    __shared__ alignas(16) __hip_bfloat16 Bsh[64][40];
    __shared__ alignas(16) __hip_bfloat16 Bsl[64][40];

    const int n0 = blockIdx.x * 64;
    const int m0 = blockIdx.y * 64;

    const int tid  = threadIdx.x;
    const int wave = tid >> 6;
    const int lane = tid & 63;
    const int lr = tid >> 2;
    const int lc = (tid & 3) * 8;
    const int wm = (wave >> 1) * 32;
    const int wn = (wave & 1) * 32;
    const int fr = lane & 15;
    const int quad = lane >> 4;

    f32x4 acc[2][2] = {};

    for (int k0 = 0; k0 < DMODEL; k0 += 32) {
        const size_t aoff = (size_t)(m0 + lr) * DMODEL + k0 + lc;
        const size_t boff = (size_t)(n0 + lr) * DMODEL + k0 + lc;
        *(uint4*)(&Ash[lr][lc]) = *(const uint4*)(Ah + aoff);
        *(uint4*)(&Asl[lr][lc]) = *(const uint4*)(Al + aoff);
        *(uint4*)(&Bsh[lr][lc]) = *(const uint4*)(Bh + boff);
        *(uint4*)(&Bsl[lr][lc]) = *(const uint4*)(Bl + boff);
        __syncthreads();

        short8 a0h = *(const short8*)(&Ash[wm + fr][quad * 8]);
        short8 a1h = *(const short8*)(&Ash[wm + 16 + fr][quad * 8]);
        short8 a0l = *(const short8*)(&Asl[wm + fr][quad * 8]);
        short8 a1l = *(const short8*)(&Asl[wm + 16 + fr][quad * 8]);
        short8 b0h = *(const short8*)(&Bsh[wn + fr][quad * 8]);
        short8 b1h = *(const short8*)(&Bsh[wn + 16 + fr][quad * 8]);
        short8 b0l = *(const short8*)(&Bsl[wn + fr][quad * 8]);
        short8 b1l = *(const short8*)(&Bsl[wn + 16 + fr][quad * 8]);

        acc[0][0] = __builtin_amdgcn_mfma_f32_16x16x32_bf16(a0l, b0h, acc[0][0], 0, 0, 0);
        acc[0][1] = __builtin_amdgcn_mfma_f32_16x16x32_bf16(a0l, b1h, acc[0][1], 0, 0, 0);
        acc[1][0] = __builtin_amdgcn_mfma_f32_16x16x32_bf16(a1l, b0h, acc[1][0], 0, 0, 0);
        acc[1][1] = __builtin_amdgcn_mfma_f32_16x16x32_bf16(a1l, b1h, acc[1][1], 0, 0, 0);
        acc[0][0] = __builtin_amdgcn_mfma_f32_16x16x32_bf16(a0h, b0l, acc[0][0], 0, 0, 0);
        acc[0][1] = __builtin_amdgcn_mfma_f32_16x16x32_bf16(a0h, b1l, acc[0][1], 0, 0, 0);
        acc[1][0] = __builtin_amdgcn_mfma_f32_16x16x32_bf16(a1h, b0l, acc[1][0], 0, 0, 0);
        acc[1][1] = __builtin_amdgcn_mfma_f32_16x16x32_bf16(a1h, b1l, acc[1][1], 0, 0, 0);
        acc[0][0] = __builtin_amdgcn_mfma_f32_16x16x32_bf16(a0h, b0h, acc[0][0], 0, 0, 0);
        acc[0][1] = __builtin_amdgcn_mfma_f32_16x16x32_bf16(a0h, b1h, acc[0][1], 0, 0, 0);
        acc[1][0] = __builtin_amdgcn_mfma_f32_16x16x32_bf16(a1h, b0h, acc[1][0], 0, 0, 0);
        acc[1][1] = __builtin_amdgcn_mfma_f32_16x16x32_bf16(a1h, b1h, acc[1][1], 0, 0, 0);
        __syncthreads();
    }

    #pragma unroll
    for (int tm = 0; tm < 2; tm++)
    #pragma unroll
    for (int tn = 0; tn < 2; tn++)
    #pragma unroll
    for (int r = 0; r < 4; r++) {
        int row = m0 + wm + tm * 16 + quad * 4 + r;
        int col = n0 + wn + tn * 16 + fr;
        C[(size_t)row * DMODEL + col] = acc[tm][tn][r];
    }
}

// ---------------------------------------------------------------------------
// Gate: softmax((x @ Wg^T).reshape(n, 16, 2), axis=-1) -> float2 per (n,h)
// ---------------------------------------------------------------------------
__global__ __launch_bounds__(256) void gate_kernel(
    const float* __restrict__ x,
    const float* __restrict__ Wg,
    float2* __restrict__ gate)
{
    __shared__ float gs[32];
    const int n = blockIdx.x;
    const int wave = threadIdx.x >> 6, lane = threadIdx.x & 63;
    #pragma unroll
    for (int jj = 0; jj < 8; jj++) {
        int j = wave * 8 + jj;
        float s = 0.f;
        #pragma unroll
        for (int t = 0; t < 16; t++) {
            int d = lane + (t << 6);
            s += x[n * DMODEL + d] * Wg[j * DMODEL + d];
        }
        #pragma unroll
        for (int off = 32; off; off >>= 1) s += __shfl_xor(s, off);
        if (lane == 0) gs[j] = s;
    }
    __syncthreads();
    if (threadIdx.x < NHEAD) {
        int h = threadIdx.x;
        float a = gs[2 * h], b = gs[2 * h + 1];
        float m = fmaxf(a, b);
        float ea = expf(a - m), eb = expf(b - m);
        float inv = 1.f / (ea + eb);
        gate[n * NHEAD + h] = make_float2(ea * inv, eb * inv);
    }
}

// ---------------------------------------------------------------------------
// k_compress[g][f] = mean over c of K[g*64+c][f]
// ---------------------------------------------------------------------------
__global__ __launch_bounds__(256) void kcompress_kernel(
    const float* __restrict__ K, float* __restrict__ kc)
{
    const int g = blockIdx.x;
    for (int f = threadIdx.x; f < DMODEL; f += 256) {
        float s = 0.f;
        #pragma unroll 8
        for (int c = 0; c < CHUNK; c++) s += K[(size_t)(g * CHUNK + c) * DMODEL + f];
        kc[g * DMODEL + f] = s * (1.0f / CHUNK);
    }
}

// ---------------------------------------------------------------------------
// Per-head transpose + pair-pack:
// Ktp[(h*32+d2)*1024 + n] = pack(bf16(K[n][h*64+2d2]), bf16(K[n][h*64+2d2+1]))
// ---------------------------------------------------------------------------
__global__ __launch_bounds__(256) void transpose_pack_k_kernel(
    const float* __restrict__ K, unsigned* __restrict__ Ktp)
{
    __shared__ float T[64][65];
    const int h = blockIdx.x & 15;
    const int n0 = (blockIdx.x >> 4) * 64;
    for (int i = threadIdx.x; i < 64 * 64; i += 256) {
        int r = i >> 6, d = i & 63;
        T[r][d] = K[(size_t)(n0 + r) * DMODEL + h * HDIM + d];
    }
    __syncthreads();
    for (int i = threadIdx.x; i < 64 * 32; i += 256) {
        int d2 = i >> 6, nn = i & 63;
        unsigned lo = bf16bits(T[nn][2 * d2]);
        unsigned hi = bf16bits(T[nn][2 * d2 + 1]);
        Ktp[(size_t)(h * 32 + d2) * NTOK + n0 + nn] = lo | (hi << 16);
    }
}

// ---------------------------------------------------------------------------
// V pair-pack over token rows: Vp[k2*1024 + f] = pack(bf16(V[2k2][f]),
// bf16(V[2k2+1][f]))   (k2 in [0,512))
// ---------------------------------------------------------------------------
__global__ __launch_bounds__(256) void pack_v_kernel(
    const float* __restrict__ V, unsigned* __restrict__ Vp)
{
    const int idx = blockIdx.x * 256 + threadIdx.x;   // [0, 512*1024)
    const int k2 = idx >> 10, f = idx & 1023;
    unsigned lo = bf16bits(V[(size_t)(2 * k2) * DMODEL + f]);
    unsigned hi = bf16bits(V[(size_t)(2 * k2 + 1) * DMODEL + f]);
    Vp[idx] = lo | (hi << 16);
}

// ---------------------------------------------------------------------------
// score + top-2 per (n,h), transposed store idx_t[h*1024+n]. EXACT f32.
// g masked if n >= 64*g; ties -> lowest index; all-masked -> (0,1).
// ---------------------------------------------------------------------------
__global__ __launch_bounds__(256) void score_top2_kernel(
    const float* __restrict__ Q, const float* __restrict__ kc,
    int2* __restrict__ idx_t)
{
    const int t = blockIdx.x * 256 + threadIdx.x;   // t = n*16 + h
    const int n = t >> 4, h = t & 15;
    float q[HDIM];
    #pragma unroll
    for (int d = 0; d < HDIM; d++) q[d] = Q[(size_t)n * DMODEL + h * HDIM + d];
    float sc[NBLK];
    #pragma unroll
    for (int g = 0; g < NBLK; g++) {
        float s = 0.f;
        #pragma unroll
        for (int d = 0; d < HDIM; d++) s += q[d] * kc[g * DMODEL + h * HDIM + d];
        sc[g] = (n >= (g << 6)) ? -INFINITY : s;
    }
    int i1 = -1; float b1 = -INFINITY;
    #pragma unroll
    for (int g = 0; g < NBLK; g++) if (i1 < 0 || sc[g] > b1) { b1 = sc[g]; i1 = g; }
    int i2 = -1; float b2 = -INFINITY;
    #pragma unroll
    for (int g = 0; g < NBLK; g++) { if (g == i1) continue; if (i2 < 0 || sc[g] > b2) { b2 = sc[g]; i2 = g; } }
    idx_t[(h << 10) | n] = make_int2(i1, i2);
}

// ---------------------------------------------------------------------------
// FUSED attention: one wave per (n,h). inter (2 blocks) + causal intra +
// gated blend, in-place over Q. Packed bf16 pairs + dot2; readlane broadcasts.
// ---------------------------------------------------------------------------
__global__ __launch_bounds__(256) void attn_fused_kernel(
    float* __restrict__ Q, const unsigned* __restrict__ Ktp,
    const unsigned* __restrict__ Vp, const int2* __restrict__ idx_t,
    const float2* __restrict__ gate)
{
    const int wave = threadIdx.x >> 6, lane = threadIdx.x & 63;
    const int gw = blockIdx.x * 4 + wave;   // = n*16 + h
    const int n = gw >> 4, h = gw & 15;
    const int qi = n & 63;
    const int rown = (n >> 6) * CHUNK;
    const int2 sel = idx_t[(h << 10) | n];
    const int r1 = sel.x * CHUNK, r2 = sel.y * CHUNK;

    const float qreg = Q[(size_t)n * DMODEL + h * HDIM + lane];
    const unsigned qpack = packpair(qreg);            // valid at even lanes
    const unsigned* Ktph = Ktp + (size_t)h * 32 * NTOK;

    // scores: lane = key index; dot2 over d-pairs
    float s0 = 0.f, s1 = 0.f, si = 0.f;
    #pragma unroll 8
    for (int d2 = 0; d2 < 32; d2++) {
        const unsigned qp = rlu(qpack, 2 * d2);
        const unsigned* row = Ktph + (size_t)d2 * NTOK;
        s0 = dot2bf(row[r1 + lane], qp, s0);
        s1 = dot2bf(row[r2 + lane], qp, s1);
        si = dot2bf(row[rown + lane], qp, si);
    }
    s0 *= 0.125f; s1 *= 0.125f; si *= 0.125f;

    // inter softmax over 128 keys (unnormalized; divide at end)
    float m = fmaxf(s0, s1);
    #pragma unroll
    for (int off = 32; off; off >>= 1) m = fmaxf(m, __shfl_xor(m, off));
    const float e0 = expf(s0 - m), e1 = expf(s1 - m);
    float sum = e0 + e1;
    #pragma unroll
    for (int off = 32; off; off >>= 1) sum += __shfl_xor(sum, off);

    // intra softmax (causal)
    float sim = (lane > qi) ? -INFINITY : si;
    float mi = sim;
    #pragma unroll
    for (int off = 32; off; off >>= 1) mi = fmaxf(mi, __shfl_xor(mi, off));
    const float ei = (lane > qi) ? 0.f : expf(si - mi);
    float sumi = ei;
    #pragma unroll
    for (int off = 32; off; off >>= 1) sumi += __shfl_xor(sumi, off);

    // pack e's as bf16 pairs (valid at even lanes)
    const unsigned e0p = packpair(e0);
    const unsigned e1p = packpair(e1);
    const unsigned eip = packpair(ei);

    // PV: lane = dim; dot2 over key-pairs
    const unsigned* Vph = Vp + h * HDIM + lane;
    float oa = 0.f, ob = 0.f, oi = 0.f;
    const int b1k = r1 >> 1, b2k = r2 >> 1, bik = rown >> 1;
    #pragma unroll 8
    for (int k2 = 0; k2 < 32; k2++) {
        oa = dot2bf(Vph[(size_t)(b1k + k2) * DMODEL], rlu(e0p, 2 * k2), oa);
        ob = dot2bf(Vph[(size_t)(b2k + k2) * DMODEL], rlu(e1p, 2 * k2), ob);
    }
    const int k2max = qi >> 1;                        // wave-uniform
    #pragma unroll 4
    for (int k2 = 0; k2 <= k2max; k2++) {
        oi = dot2bf(Vph[(size_t)(bik + k2) * DMODEL], rlu(eip, 2 * k2), oi);
    }

    const float2 gt = gate[gw];
    const float val = gt.x * ((oa + ob) / sum) + gt.y * (oi / sumi);
    Q[(size_t)n * DMODEL + h * HDIM + lane] = val;
}

// ---------------------------------------------------------------------------
extern "C" void kernel_launch(void* const* d_in, const int* in_sizes, int n_in,
                              void* d_out, int out_size, void* d_ws, size_t ws_size,
                              hipStream_t stream)
{
    const float* x  = (const float*)d_in[0];
    const float* Wq = (const float*)d_in[1];
    const float* Wk = (const float*)d_in[2];
    const float* Wv = (const float*)d_in[3];
    const float* Wg = (const float*)d_in[4];
    const float* Wo = (const float*)d_in[5];

    const size_t M1 = (size_t)NTOK * DMODEL;   // 1M elems

    // workspace layout (~32.3 MB)
    float* Q       = (float*)d_ws;                    // 4 MB (becomes blended o)
    float* K       = Q + M1;                          // 4 MB
    float* V       = K + M1;                          // 4 MB
    unsigned* Ktp  = (unsigned*)(V + M1);             // 2 MB (packed bf16 pairs)
    unsigned* Vp   = Ktp + (M1 >> 1);                 // 2 MB
    float* kc      = (float*)(Vp + (M1 >> 1));        // 64 KB
    float2* gate   = (float2*)(kc + NBLK * DMODEL);   // 128 KB
    int2* idx_t    = (int2*)(gate + NTOK * NHEAD);    // 128 KB
    __hip_bfloat16* xh  = (__hip_bfloat16*)(idx_t + NTOK * NHEAD);  // 2 MB (later: o hi)
    __hip_bfloat16* xl  = xh + M1;                                   // 2 MB (later: o lo)
    __hip_bfloat16* W3h = xl + M1;                                   // 6 MB (later: Wo hi)
    __hip_bfloat16* W3l = W3h + 3 * M1;                              // 6 MB (later: Wo lo)

    cast_all_kernel<<<4 * 1024, 256, 0, stream>>>(x, Wq, Wk, Wv, xh, xl, W3h, W3l);

    dim3 gqkv(48, 16);
    gemm_qkv_ps<<<gqkv, 256, 0, stream>>>(xh, xl, W3h, W3l, Q, K, V);

    gate_kernel<<<NTOK, 256, 0, stream>>>(x, Wg, gate);
    kcompress_kernel<<<NBLK, 256, 0, stream>>>(K, kc);
    transpose_pack_k_kernel<<<256, 256, 0, stream>>>(K, Ktp);
    pack_v_kernel<<<2048, 256, 0, stream>>>(V, Vp);
    score_top2_kernel<<<NTOK * NHEAD / 256, 256, 0, stream>>>(Q, kc, idx_t);
    attn_fused_kernel<<<NTOK * NHEAD / 4, 256, 0, stream>>>(Q, Ktp, Vp, idx_t, gate);

    cast_owo_kernel<<<2 * 1024, 256, 0, stream>>>(Q, Wo, xh, xl, W3h, W3l);

    dim3 gwo(16, 16);
    gemm_wo_ps<<<gwo, 256, 0, stream>>>(xh, xl, W3h, W3l, (float*)d_out);
}

// Round 12
// 210.956 us; speedup vs baseline: 1.3953x; 1.0842x over previous
//
#include <hip/hip_runtime.h>
#include <hip/hip_bf16.h>
#include <math.h>

// Problem: B=1, N=1024, D=1024, H=16, C=64, TOPK=2, HD=64, G=16
// Inputs (float32): x, Wq, Wk, Wv [1024x1024], Wg[32,1024], Wo[1024,1024]
// Output (float32): [1024,1024]
//
// Q proj + Wo proj: bf16x2 split MFMA (3 terms). K,V proj: plain bf16 MFMA
// with epilogues writing packed-bf16-pair buffers directly (Ktp transposed,
// Vp row-paired). kc computed EXACTLY as (chunk-mean x) @ Wk^T in f32 VALU
// (k_compress is linear), so selection needs no K precision. Attention:
// one wave per (n,h), dot2 bf16 pairs, readlane broadcasts; writes split o.

typedef __attribute__((ext_vector_type(8))) short short8;   // 8 bf16 = 4 VGPRs
typedef __attribute__((ext_vector_type(4))) float f32x4;
typedef __attribute__((ext_vector_type(2))) __bf16 bf16x2v;

#define NTOK 1024
#define DMODEL 1024
#define NHEAD 16
#define HDIM 64
#define CHUNK 64
#define NBLK 16

__device__ __forceinline__ unsigned rlu(unsigned v, int l)
{
    return (unsigned)__builtin_amdgcn_readlane((int)v, l);
}

__device__ __forceinline__ unsigned short bf16bits(float v)
{
    __hip_bfloat16 h = __float2bfloat16(v);
    return __builtin_bit_cast(unsigned short, h);
}

// acc += a.lo*b.lo + a.hi*b.hi  (bf16 pairs packed in uints)
__device__ __forceinline__ float dot2bf(unsigned a, unsigned b, float acc)
{
#if __has_builtin(__builtin_amdgcn_fdot2_f32_bf16)
    return __builtin_amdgcn_fdot2_f32_bf16(
        __builtin_bit_cast(bf16x2v, a), __builtin_bit_cast(bf16x2v, b), acc, false);
#else
    float a0 = __uint_as_float(a << 16), a1 = __uint_as_float(a & 0xffff0000u);
    float b0 = __uint_as_float(b << 16), b1 = __uint_as_float(b & 0xffff0000u);
    return acc + a0 * b0 + a1 * b1;
#endif
}

// pack (own, lane^1) bf16 bits into a uint; valid at EVEN lanes (own=low)
__device__ __forceinline__ unsigned packpair(float v)
{
    unsigned b = bf16bits(v);
    unsigned nb = (unsigned)__shfl_xor((int)b, 1) & 0xffffu;
    return b | (nb << 16);
}

// ---------------------------------------------------------------------------
// Merged pre-cast. which = blockIdx.x>>10:
// 0: x split  1: Wq split  2: Wo split  3: Wk hi  4: Wv hi
// ---------------------------------------------------------------------------
__global__ __launch_bounds__(256) void cast_all_kernel(
    const float* __restrict__ x,  const float* __restrict__ Wq,
    const float* __restrict__ Wk, const float* __restrict__ Wv,
    const float* __restrict__ Wo,
    __hip_bfloat16* __restrict__ xh,  __hip_bfloat16* __restrict__ xl,
    __hip_bfloat16* __restrict__ Wqh, __hip_bfloat16* __restrict__ Wql,
    __hip_bfloat16* __restrict__ Woh, __hip_bfloat16* __restrict__ Wol,
    __hip_bfloat16* __restrict__ Wkh, __hip_bfloat16* __restrict__ Wvh)
{
    const int which = blockIdx.x >> 10;
    const int b = blockIdx.x & 1023;
    const int i = (b * 256 + threadIdx.x) * 4;
    const float* in; __hip_bfloat16 *hi, *lo;
    if (which == 0)      { in = x;  hi = xh;  lo = xl;  }
    else if (which == 1) { in = Wq; hi = Wqh; lo = Wql; }
    else if (which == 2) { in = Wo; hi = Woh; lo = Wol; }
    else if (which == 3) { in = Wk; hi = Wkh; lo = nullptr; }
    else                 { in = Wv; hi = Wvh; lo = nullptr; }

    float4 v = *(const float4*)(in + i);
    float vv[4] = {v.x, v.y, v.z, v.w};
    __hip_bfloat16 h[4], l[4];
    #pragma unroll
    for (int j = 0; j < 4; j++) {
        h[j] = __float2bfloat16(vv[j]);
        l[j] = __float2bfloat16(vv[j] - __bfloat162float(h[j]));
    }
    *(uint2*)(hi + i) = *(uint2*)h;
    if (lo) *(uint2*)(lo + i) = *(uint2*)l;
}

// ---------------------------------------------------------------------------
// xm[g][f] = mean over c of x[g*64+c][f]  (exact f32). grid 64 = 16g x 4fc.
// ---------------------------------------------------------------------------
__global__ __launch_bounds__(256) void xm_kernel(
    const float* __restrict__ x, float* __restrict__ xm)
{
    const int g = blockIdx.x >> 2;
    const int f = (blockIdx.x & 3) * 256 + threadIdx.x;
    float s = 0.f;
    #pragma unroll 8
    for (int c = 0; c < CHUNK; c++) s += x[(size_t)(g * CHUNK + c) * DMODEL + f];
    xm[g * DMODEL + f] = s * (1.0f / CHUNK);
}

// ---------------------------------------------------------------------------
// kc = xm @ Wk^T  (exact f32; k_compress is linear in x). One block per f;
// thread (g = tid>>4, sub = tid&15) partial-dots, 16-lane shfl reduce.
// ---------------------------------------------------------------------------
__global__ __launch_bounds__(256) void kc_gemm_kernel(
    const float* __restrict__ xm, const float* __restrict__ Wk,
    float* __restrict__ kc)
{
    const int f = blockIdx.x;
    const int g = threadIdx.x >> 4;
    const int sub = threadIdx.x & 15;
    const float* wrow = Wk + (size_t)f * DMODEL;
    float s = 0.f;
    #pragma unroll 16
    for (int i = 0; i < 64; i++) {
        int e = i * 16 + sub;                 // coalesced across sub
        s += xm[g * DMODEL + e] * wrow[e];
    }
    #pragma unroll
    for (int off = 8; off; off >>= 1) s += __shfl_xor(s, off);
    if (sub == 0) kc[g * DMODEL + f] = s;
}

// ---------------------------------------------------------------------------
// QKV GEMM, 64x64 tile. widx = blockIdx.x>>4:
//  0: Q = x@Wq^T, split (12 MFMA/iter), f32 store.
//  1: K = x@Wk^T, bf16 (4 MFMA/iter), epilogue -> Ktp packed transposed.
//  2: V = x@Wv^T, bf16 (4 MFMA/iter), epilogue -> Vp packed row-pairs.
// ---------------------------------------------------------------------------
__global__ __launch_bounds__(256) void gemm_qkv_ps(
    const __hip_bfloat16* __restrict__ xh, const __hip_bfloat16* __restrict__ xl,
    const __hip_bfloat16* __restrict__ Wqh, const __hip_bfloat16* __restrict__ Wql,
    const __hip_bfloat16* __restrict__ Wkh, const __hip_bfloat16* __restrict__ Wvh,
    float* __restrict__ Q, unsigned* __restrict__ Ktp, unsigned* __restrict__ Vp)
{
    __shared__ alignas(16) __hip_bfloat16 Ash[64][40];
    __shared__ alignas(16) __hip_bfloat16 Asl[64][40];
    __shared__ alignas(16) __hip_bfloat16 Bsh[64][40];
    __shared__ alignas(16) __hip_bfloat16 Bsl[64][40];

    const int widx = blockIdx.x >> 4;
    const __hip_bfloat16* __restrict__ Bh =
        (widx == 0) ? Wqh : (widx == 1) ? Wkh : Wvh;
    const int n0 = (blockIdx.x & 15) * 64;
    const int m0 = blockIdx.y * 64;

    const int tid  = threadIdx.x;
    const int wave = tid >> 6;
    const int lane = tid & 63;
    const int lr = tid >> 2;
    const int lc = (tid & 3) * 8;
    const int wm = (wave >> 1) * 32;
    const int wn = (wave & 1) * 32;
    const int fr = lane & 15;
    const int quad = lane >> 4;

    f32x4 acc[2][2] = {};

    if (widx == 0) {
        for (int k0 = 0; k0 < DMODEL; k0 += 32) {
            const size_t aoff = (size_t)(m0 + lr) * DMODEL + k0 + lc;
            const size_t boff = (size_t)(n0 + lr) * DMODEL + k0 + lc;
            *(uint4*)(&Ash[lr][lc]) = *(const uint4*)(xh + aoff);
            *(uint4*)(&Asl[lr][lc]) = *(const uint4*)(xl + aoff);
            *(uint4*)(&Bsh[lr][lc]) = *(const uint4*)(Bh + boff);
            *(uint4*)(&Bsl[lr][lc]) = *(const uint4*)(Wql + boff);
            __syncthreads();

            short8 a0h = *(const short8*)(&Ash[wm + fr][quad * 8]);
            short8 a1h = *(const short8*)(&Ash[wm + 16 + fr][quad * 8]);
            short8 a0l = *(const short8*)(&Asl[wm + fr][quad * 8]);
            short8 a1l = *(const short8*)(&Asl[wm + 16 + fr][quad * 8]);
            short8 b0h = *(const short8*)(&Bsh[wn + fr][quad * 8]);
            short8 b1h = *(const short8*)(&Bsh[wn + 16 + fr][quad * 8]);
            short8 b0l = *(const short8*)(&Bsl[wn + fr][quad * 8]);
            short8 b1l = *(const short8*)(&Bsl[wn + 16 + fr][quad * 8]);

            acc[0][0] = __builtin_amdgcn_mfma_f32_16x16x32_bf16(a0l, b0h, acc[0][0], 0, 0, 0);
            acc[0][1] = __builtin_amdgcn_mfma_f32_16x16x32_bf16(a0l, b1h, acc[0][1], 0, 0, 0);
            acc[1][0] = __builtin_amdgcn_mfma_f32_16x16x32_bf16(a1l, b0h, acc[1][0], 0, 0, 0);
            acc[1][1] = __builtin_amdgcn_mfma_f32_16x16x32_bf16(a1l, b1h, acc[1][1], 0, 0, 0);
            acc[0][0] = __builtin_amdgcn_mfma_f32_16x16x32_bf16(a0h, b0l, acc[0][0], 0, 0, 0);
            acc[0][1] = __builtin_amdgcn_mfma_f32_16x16x32_bf16(a0h, b1l, acc[0][1], 0, 0, 0);
            acc[1][0] = __builtin_amdgcn_mfma_f32_16x16x32_bf16(a1h, b0l, acc[1][0], 0, 0, 0);
            acc[1][1] = __builtin_amdgcn_mfma_f32_16x16x32_bf16(a1h, b1l, acc[1][1], 0, 0, 0);
            acc[0][0] = __builtin_amdgcn_mfma_f32_16x16x32_bf16(a0h, b0h, acc[0][0], 0, 0, 0);
            acc[0][1] = __builtin_amdgcn_mfma_f32_16x16x32_bf16(a0h, b1h, acc[0][1], 0, 0, 0);
            acc[1][0] = __builtin_amdgcn_mfma_f32_16x16x32_bf16(a1h, b0h, acc[1][0], 0, 0, 0);
            acc[1][1] = __builtin_amdgcn_mfma_f32_16x16x32_bf16(a1h, b1h, acc[1][1], 0, 0, 0);
            __syncthreads();
        }
    } else {
        for (int k0 = 0; k0 < DMODEL; k0 += 32) {
            const size_t aoff = (size_t)(m0 + lr) * DMODEL + k0 + lc;
            const size_t boff = (size_t)(n0 + lr) * DMODEL + k0 + lc;
            *(uint4*)(&Ash[lr][lc]) = *(const uint4*)(xh + aoff);
            *(uint4*)(&Bsh[lr][lc]) = *(const uint4*)(Bh + boff);
            __syncthreads();

            short8 a0h = *(const short8*)(&Ash[wm + fr][quad * 8]);
            short8 a1h = *(const short8*)(&Ash[wm + 16 + fr][quad * 8]);
            short8 b0h = *(const short8*)(&Bsh[wn + fr][quad * 8]);
            short8 b1h = *(const short8*)(&Bsh[wn + 16 + fr][quad * 8]);

            acc[0][0] = __builtin_amdgcn_mfma_f32_16x16x32_bf16(a0h, b0h, acc[0][0], 0, 0, 0);
            acc[0][1] = __builtin_amdgcn_mfma_f32_16x16x32_bf16(a0h, b1h, acc[0][1], 0, 0, 0);
            acc[1][0] = __builtin_amdgcn_mfma_f32_16x16x32_bf16(a1h, b0h, acc[1][0], 0, 0, 0);
            acc[1][1] = __builtin_amdgcn_mfma_f32_16x16x32_bf16(a1h, b1h, acc[1][1], 0, 0, 0);
            __syncthreads();
        }
    }

    if (widx == 0) {
        #pragma unroll
        for (int tm = 0; tm < 2; tm++)
        #pragma unroll
        for (int tn = 0; tn < 2; tn++)
        #pragma unroll
        for (int r = 0; r < 4; r++) {
            int row = m0 + wm + tm * 16 + quad * 4 + r;
            int col = n0 + wn + tn * 16 + fr;
            Q[(size_t)row * DMODEL + col] = acc[tm][tn][r];
        }
    } else if (widx == 1) {
        // Ktp[(f>>1)*NTOK + n] = pack(bf16(K[n][f_even]), bf16(K[n][f_odd]))
        #pragma unroll
        for (int tm = 0; tm < 2; tm++)
        #pragma unroll
        for (int tn = 0; tn < 2; tn++)
        #pragma unroll
        for (int r = 0; r < 4; r++) {
            float v = acc[tm][tn][r];
            float nb = __shfl_xor(v, 1);          // neighbor column value
            if (!(fr & 1)) {
                int f = n0 + wn + tn * 16 + fr;   // even
                int n = m0 + wm + tm * 16 + quad * 4 + r;
                unsigned p = (unsigned)bf16bits(v) | ((unsigned)bf16bits(nb) << 16);
                Ktp[(size_t)(f >> 1) * NTOK + n] = p;
            }
        }
    } else {
        // Vp[(row>>1)*DMODEL + col] = pack(bf16(V[row]), bf16(V[row+1]))
        #pragma unroll
        for (int tm = 0; tm < 2; tm++)
        #pragma unroll
        for (int tn = 0; tn < 2; tn++)
        #pragma unroll
        for (int rp = 0; rp < 2; rp++) {
            int row = m0 + wm + tm * 16 + quad * 4 + 2 * rp;   // even
            int col = n0 + wn + tn * 16 + fr;
            unsigned p = (unsigned)bf16bits(acc[tm][tn][2 * rp]) |
                         ((unsigned)bf16bits(acc[tm][tn][2 * rp + 1]) << 16);
            Vp[(size_t)(row >> 1) * DMODEL + col] = p;
        }
    }
}

// ---------------------------------------------------------------------------
// Wo GEMM (split operands), 64x64 tile, direct f32 store to d_out.
// ---------------------------------------------------------------------------
__global__ __launch_bounds__(256) void gemm_wo_ps(
    const __hip_bfloat16* __restrict__ Ah, const __hip_bfloat16* __restrict__ Al,
    const __hip_bfloat16* __restrict__ Bh, const __hip_bfloat16* __restrict__ Bl,
    float* __restrict__ C)
{
    __shared__ alignas(16) __hip_bfloat16 Ash[64][40];
    __shared__ alignas(16) __hip_bfloat16 Asl[64][40];
    __shared__ alignas(16) __hip_bfloat16 Bsh[64][40];
    __shared__ alignas(16) __hip_bfloat16 Bsl[64][40];

    const int n0 = blockIdx.x * 64;
    const int m0 = blockIdx.y * 64;

    const int tid  = threadIdx.x;
    const int wave = tid >> 6;
    const int lane = tid & 63;
    const int lr = tid >> 2;
    const int lc = (tid & 3) * 8;
    const int wm = (wave >> 1) * 32;
    const int wn = (wave & 1) * 32;
    const int fr = lane & 15;
    const int quad = lane >> 4;

    f32x4 acc[2][2] = {};

    for (int k0 = 0; k0 < DMODEL; k0 += 32) {
        const size_t aoff = (size_t)(m0 + lr) * DMODEL + k0 + lc;
        const size_t boff = (size_t)(n0 + lr) * DMODEL + k0 + lc;
        *(uint4*)(&Ash[lr][lc]) = *(const uint4*)(Ah + aoff);
        *(uint4*)(&Asl[lr][lc]) = *(const uint4*)(Al + aoff);
        *(uint4*)(&Bsh[lr][lc]) = *(const uint4*)(Bh + boff);
        *(uint4*)(&Bsl[lr][lc]) = *(const uint4*)(Bl + boff);
        __syncthreads();

        short8 a0h = *(const short8*)(&Ash[wm + fr][quad * 8]);
        short8 a1h = *(const short8*)(&Ash[wm + 16 + fr][quad * 8]);
        short8 a0l = *(const short8*)(&Asl[wm + fr][quad * 8]);
        short8 a1l = *(const short8*)(&Asl[wm + 16 + fr][quad * 8]);
        short8 b0h = *(const short8*)(&Bsh[wn + fr][quad * 8]);
        short8 b1h = *(const short8*)(&Bsh[wn + 16 + fr][quad * 8]);
        short8 b0l = *(const short8*)(&Bsl[wn + fr][quad * 8]);
        short8 b1l = *(const short8*)(&Bsl[wn + 16 + fr][quad * 8]);

        acc[0][0] = __builtin_amdgcn_mfma_f32_16x16x32_bf16(a0l, b0h, acc[0][0], 0, 0, 0);
        acc[0][1] = __builtin_amdgcn_mfma_f32_16x16x32_bf16(a0l, b1h, acc[0][1], 0, 0, 0);
        acc[1][0] = __builtin_amdgcn_mfma_f32_16x16x32_bf16(a1l, b0h, acc[1][0], 0, 0, 0);
        acc[1][1] = __builtin_amdgcn_mfma_f32_16x16x32_bf16(a1l, b1h, acc[1][1], 0, 0, 0);
        acc[0][0] = __builtin_amdgcn_mfma_f32_16x16x32_bf16(a0h, b0l, acc[0][0], 0, 0, 0);
        acc[0][1] = __builtin_amdgcn_mfma_f32_16x16x32_bf16(a0h, b1l, acc[0][1], 0, 0, 0);
        acc[1][0] = __builtin_amdgcn_mfma_f32_16x16x32_bf16(a1h, b0l, acc[1][0], 0, 0, 0);
        acc[1][1] = __builtin_amdgcn_mfma_f32_16x16x32_bf16(a1h, b1l, acc[1][1], 0, 0, 0);
        acc[0][0] = __builtin_amdgcn_mfma_f32_16x16x32_bf16(a0h, b0h, acc[0][0], 0, 0, 0);
        acc[0][1] = __builtin_amdgcn_mfma_f32_16x16x32_bf16(a0h, b1h, acc[0][1], 0, 0, 0);
        acc[1][0] = __builtin_amdgcn_mfma_f32_16x16x32_bf16(a1h, b0h, acc[1][0], 0, 0, 0);
        acc[1][1] = __builtin_amdgcn_mfma_f32_16x16x32_bf16(a1h, b1h, acc[1][1], 0, 0, 0);
        __syncthreads();
    }

    #pragma unroll
    for (int tm = 0; tm < 2; tm++)
    #pragma unroll
    for (int tn = 0; tn < 2; tn++)
    #pragma unroll
    for (int r = 0; r < 4; r++) {
        int row = m0 + wm + tm * 16 + quad * 4 + r;
        int col = n0 + wn + tn * 16 + fr;
        C[(size_t)row * DMODEL + col] = acc[tm][tn][r];
    }
}

// ---------------------------------------------------------------------------
// Gate: softmax((x @ Wg^T).reshape(n, 16, 2), axis=-1) -> float2 per (n,h)
// ---------------------------------------------------------------------------
__global__ __launch_bounds__(256) void gate_kernel(
    const float* __restrict__ x,
    const float* __restrict__ Wg,
    float2* __restrict__ gate)
{
    __shared__ float gs[32];
    const int n = blockIdx.x;
    const int wave = threadIdx.x >> 6, lane = threadIdx.x & 63;
    #pragma unroll
    for (int jj = 0; jj < 8; jj++) {
        int j = wave * 8 + jj;
        float s = 0.f;
        #pragma unroll
        for (int t = 0; t < 16; t++) {
            int d = lane + (t << 6);
            s += x[n * DMODEL + d] * Wg[j * DMODEL + d];
        }
        #pragma unroll
        for (int off = 32; off; off >>= 1) s += __shfl_xor(s, off);
        if (lane == 0) gs[j] = s;
    }
    __syncthreads();
    if (threadIdx.x < NHEAD) {
        int h = threadIdx.x;
        float a = gs[2 * h], b = gs[2 * h + 1];
        float m = fmaxf(a, b);
        float ea = expf(a - m), eb = expf(b - m);
        float inv = 1.f / (ea + eb);
        gate[n * NHEAD + h] = make_float2(ea * inv, eb * inv);
    }
}

// ---------------------------------------------------------------------------
// score + top-2 per (n,h), transposed store idx_t[h*1024+n]. EXACT f32.
// g masked if n >= 64*g; ties -> lowest index; all-masked -> (0,1).
// ---------------------------------------------------------------------------
__global__ __launch_bounds__(256) void score_top2_kernel(
    const float* __restrict__ Q, const float* __restrict__ kc,
    int2* __restrict__ idx_t)
{
    const int t = blockIdx.x * 256 + threadIdx.x;   // t = n*16 + h
    const int n = t >> 4, h = t & 15;
    float q[HDIM];
    #pragma unroll
    for (int d = 0; d < HDIM; d++) q[d] = Q[(size_t)n * DMODEL + h * HDIM + d];
    float sc[NBLK];
    #pragma unroll
    for (int g = 0; g < NBLK; g++) {
        float s = 0.f;
        #pragma unroll
        for (int d = 0; d < HDIM; d++) s += q[d] * kc[g * DMODEL + h * HDIM + d];
        sc[g] = (n >= (g << 6)) ? -INFINITY : s;
    }
    int i1 = -1; float b1 = -INFINITY;
    #pragma unroll
    for (int g = 0; g < NBLK; g++) if (i1 < 0 || sc[g] > b1) { b1 = sc[g]; i1 = g; }
    int i2 = -1; float b2 = -INFINITY;
    #pragma unroll
    for (int g = 0; g < NBLK; g++) { if (g == i1) continue; if (i2 < 0 || sc[g] > b2) { b2 = sc[g]; i2 = g; } }
    idx_t[(h << 10) | n] = make_int2(i1, i2);
}

// ---------------------------------------------------------------------------
// FUSED attention: one wave per (n,h). inter (2 blocks) + causal intra +
// gated blend. Packed bf16 pairs + dot2; readlane broadcasts. Writes split o.
// ---------------------------------------------------------------------------
__global__ __launch_bounds__(256) void attn_fused_kernel(
    const float* __restrict__ Q, const unsigned* __restrict__ Ktp,
    const unsigned* __restrict__ Vp, const int2* __restrict__ idx_t,
    const float2* __restrict__ gate,
    __hip_bfloat16* __restrict__ oh, __hip_bfloat16* __restrict__ ol)
{
    const int wave = threadIdx.x >> 6, lane = threadIdx.x & 63;
    const int gw = blockIdx.x * 4 + wave;   // = n*16 + h
    const int n = gw >> 4, h = gw & 15;
    const int qi = n & 63;
    const int rown = (n >> 6) * CHUNK;
    const int2 sel = idx_t[(h << 10) | n];
    const int r1 = sel.x * CHUNK, r2 = sel.y * CHUNK;

    const float qreg = Q[(size_t)n * DMODEL + h * HDIM + lane];
    const unsigned qpack = packpair(qreg);            // valid at even lanes
    const unsigned* Ktph = Ktp + (size_t)h * 32 * NTOK;

    float s0 = 0.f, s1 = 0.f, si = 0.f;
    #pragma unroll 8
    for (int d2 = 0; d2 < 32; d2++) {
        const unsigned qp = rlu(qpack, 2 * d2);
        const unsigned* row = Ktph + (size_t)d2 * NTOK;
        s0 = dot2bf(row[r1 + lane], qp, s0);
        s1 = dot2bf(row[r2 + lane], qp, s1);
        si = dot2bf(row[rown + lane], qp, si);
    }
    s0 *= 0.125f; s1 *= 0.125f; si *= 0.125f;

    float m = fmaxf(s0, s1);
    #pragma unroll
    for (int off = 32; off; off >>= 1) m = fmaxf(m, __shfl_xor(m, off));
    const float e0 = expf(s0 - m), e1 = expf(s1 - m);
    float sum = e0 + e1;
    #pragma unroll
    for (int off = 32; off; off >>= 1) sum += __shfl_xor(sum, off);

    float sim = (lane > qi) ? -INFINITY : si;
    float mi = sim;
    #pragma unroll
    for (int off = 32; off; off >>= 1) mi = fmaxf(mi, __shfl_xor(mi, off));
    const float ei = (lane > qi) ? 0.f : expf(si - mi);
    float sumi = ei;
    #pragma unroll
    for (int off = 32; off; off >>= 1) sumi += __shfl_xor(sumi, off);

    const unsigned e0p = packpair(e0);
    const unsigned e1p = packpair(e1);
    const unsigned eip = packpair(ei);

    const unsigned* Vph = Vp + h * HDIM + lane;
    float oa = 0.f, ob = 0.f, oi = 0.f;
    const int b1k = r1 >> 1, b2k = r2 >> 1, bik = rown >> 1;
    #pragma unroll 8
    for (int k2 = 0; k2 < 32; k2++) {
        oa = dot2bf(Vph[(size_t)(b1k + k2) * DMODEL], rlu(e0p, 2 * k2), oa);
        ob = dot2bf(Vph[(size_t)(b2k + k2) * DMODEL], rlu(e1p, 2 * k2), ob);
    }
    const int k2max = qi >> 1;                        // wave-uniform
    #pragma unroll 4
    for (int k2 = 0; k2 <= k2max; k2++) {
        oi = dot2bf(Vph[(size_t)(bik + k2) * DMODEL], rlu(eip, 2 * k2), oi);
    }

    const float2 gt = gate[gw];
    const float val = gt.x * ((oa + ob) / sum) + gt.y * (oi / sumi);
    const size_t oidx = (size_t)n * DMODEL + h * HDIM + lane;
    __hip_bfloat16 hv = __float2bfloat16(val);
    oh[oidx] = hv;
    ol[oidx] = __float2bfloat16(val - __bfloat162float(hv));
}

// ---------------------------------------------------------------------------
extern "C" void kernel_launch(void* const* d_in, const int* in_sizes, int n_in,
                              void* d_out, int out_size, void* d_ws, size_t ws_size,
                              hipStream_t stream)
{
    const float* x  = (const float*)d_in[0];
    const float* Wq = (const float*)d_in[1];
    const float* Wk = (const float*)d_in[2];
    const float* Wv = (const float*)d_in[3];
    const float* Wg = (const float*)d_in[4];
    const float* Wo = (const float*)d_in[5];

    const size_t M1 = (size_t)NTOK * DMODEL;   // 1M elems

    // workspace layout (~28.5 MB)
    float* Q       = (float*)d_ws;                    // 4 MB
    unsigned* Ktp  = (unsigned*)(Q + M1);             // 2 MB
    unsigned* Vp   = Ktp + (M1 >> 1);                 // 2 MB
    float* xm      = (float*)(Vp + (M1 >> 1));        // 64 KB
    float* kc      = xm + NBLK * DMODEL;              // 64 KB
    float2* gate   = (float2*)(kc + NBLK * DMODEL);   // 128 KB
    int2* idx_t    = (int2*)(gate + NTOK * NHEAD);    // 128 KB
    __hip_bfloat16* xh  = (__hip_bfloat16*)(idx_t + NTOK * NHEAD);  // 2 MB
    __hip_bfloat16* xl  = xh + M1;     // 2 MB
    __hip_bfloat16* Wqh = xl + M1;     // 2 MB
    __hip_bfloat16* Wql = Wqh + M1;    // 2 MB
    __hip_bfloat16* Woh = Wql + M1;    // 2 MB
    __hip_bfloat16* Wol = Woh + M1;    // 2 MB
    __hip_bfloat16* Wkh = Wol + M1;    // 2 MB
    __hip_bfloat16* Wvh = Wkh + M1;    // 2 MB
    __hip_bfloat16* oh  = Wvh + M1;    // 2 MB
    __hip_bfloat16* ol  = oh + M1;     // 2 MB

    cast_all_kernel<<<5 * 1024, 256, 0, stream>>>(
        x, Wq, Wk, Wv, Wo, xh, xl, Wqh, Wql, Woh, Wol, Wkh, Wvh);

    xm_kernel<<<64, 256, 0, stream>>>(x, xm);
    kc_gemm_kernel<<<1024, 256, 0, stream>>>(xm, Wk, kc);
    gate_kernel<<<NTOK, 256, 0, stream>>>(x, Wg, gate);

    dim3 gqkv(48, 16);
    gemm_qkv_ps<<<gqkv, 256, 0, stream>>>(xh, xl, Wqh, Wql, Wkh, Wvh, Q, Ktp, Vp);

    score_top2_kernel<<<NTOK * NHEAD / 256, 256, 0, stream>>>(Q, kc, idx_t);
    attn_fused_kernel<<<NTOK * NHEAD / 4, 256, 0, stream>>>(Q, Ktp, Vp, idx_t, gate, oh, ol);

    dim3 gwo(16, 16);
    gemm_wo_ps<<<gwo, 256, 0, stream>>>(oh, ol, Woh, Wol, (float*)d_out);
}